// Round 6
// baseline (477.680 us; speedup 1.0000x reference)
//
#include <hip/hip_runtime.h>
#include <hip/hip_bf16.h>
#include <cstdint>
#include <cstddef>

// Inputs/outputs fp32 (reference dtype). Node features for the gather phase are
// stored int8 with per-row scale (round-5 evidence: agg_gather is bound by
// L2-miss fetch bytes of the random row gathers, not by VALU issue).
static constexpr int FIN = 128;
static constexpr int HC1 = 128;  // layer1: H=2, C=64, concat
static constexpr int EPB = 4096; // edges per block in bucket_scatter

__device__ __forceinline__ float bf2f(unsigned int u) { return __uint_as_float(u << 16); }
__device__ __forceinline__ unsigned short f2bf(float f) {  // round-to-nearest-even
  unsigned int u = __float_as_uint(f);
  return (unsigned short)((u + 0x7fff + ((u >> 16) & 1)) >> 16);
}
__device__ __forceinline__ float lrelu02(float x) { return x > 0.f ? x : 0.2f * x; }
__device__ __forceinline__ int rl_i(int v, int l) { return __builtin_amdgcn_readlane(v, l); }
__device__ __forceinline__ float rl_f(float v, int l) {
  return __int_as_float(__builtin_amdgcn_readlane(__float_as_int(v), l));
}
__device__ __forceinline__ unsigned int q8(float x, float inv) {
  float q = fminf(fmaxf(x * inv, -127.f), 127.f);
  return (unsigned int)((int)rintf(q) & 255);
}
#define NEG_INF __int_as_float(0xff800000)

// ============================ bucket-sorted CSR build ============================
__global__ __launch_bounds__(256) void bucket_hist(const int* __restrict__ dst,
                                                   int* __restrict__ bhist, int E, int NB) {
  __shared__ int lh[512];
  int t = threadIdx.x;
  lh[t] = 0; lh[t + 256] = 0;
  __syncthreads();
  int e0 = blockIdx.x * EPB;
  #pragma unroll
  for (int i = 0; i < EPB / 256; i++) {
    int e = e0 + i * 256 + t;
    if (e < E) atomicAdd(&lh[dst[e] >> 8], 1);
  }
  __syncthreads();
  for (int x = t; x < NB; x += 256) {
    int c = lh[x];
    if (c > 0) atomicAdd(&bhist[x], c);
  }
}

__global__ __launch_bounds__(512) void scan_buckets(const int* __restrict__ bhist,
                                                    int* __restrict__ boffs, int n) {
  __shared__ int sh[512];
  int t = threadIdx.x;
  int v = (t < n) ? bhist[t] : 0;
  sh[t] = v; __syncthreads();
  for (int d = 1; d < 512; d <<= 1) {
    int w = (t >= d) ? sh[t - d] : 0;
    __syncthreads();
    sh[t] += w;
    __syncthreads();
  }
  if (t <= n) boffs[t] = sh[t] - v;
}

__global__ __launch_bounds__(256) void bucket_scatter(const int* __restrict__ src,
                                                      const int* __restrict__ dst,
                                                      const int* __restrict__ boffs,
                                                      int* __restrict__ gcur,
                                                      unsigned int* __restrict__ sorted,
                                                      int E, int NB) {
  __shared__ int lh[512];
  int t = threadIdx.x;
  lh[t] = 0; lh[t + 256] = 0;
  __syncthreads();
  int e0 = blockIdx.x * EPB;
  #pragma unroll
  for (int i = 0; i < EPB / 256; i++) {
    int e = e0 + i * 256 + t;
    if (e < E) atomicAdd(&lh[dst[e] >> 8], 1);
  }
  __syncthreads();
  for (int x = t; x < NB; x += 256) {
    int c = lh[x];
    lh[x] = (c > 0) ? (boffs[x] + atomicAdd(&gcur[x], c)) : 0;
  }
  __syncthreads();
  #pragma unroll
  for (int i = 0; i < EPB / 256; i++) {
    int e = e0 + i * 256 + t;
    if (e < E) {
      int d = dst[e];
      int pos = atomicAdd(&lh[d >> 8], 1);
      sorted[pos] = ((unsigned int)src[e] << 8) | (unsigned int)(d & 255);
    }
  }
}

__global__ __launch_bounds__(256) void bucket_count(const unsigned int* __restrict__ sorted,
                                                    const int* __restrict__ boffs,
                                                    int* __restrict__ counts, int N) {
  __shared__ int cnt[256];
  int b = blockIdx.x, t = threadIdx.x;
  cnt[t] = 0; __syncthreads();
  int beg = boffs[b], end = boffs[b + 1];
  for (int p = beg + t; p < end; p += 256)
    atomicAdd(&cnt[sorted[p] & 255u], 1);
  __syncthreads();
  int d = b * 256 + t;
  if (d < N) counts[d] = cnt[t];
}

__global__ __launch_bounds__(256) void scan_block(const int* __restrict__ cnt,
                                                  int* __restrict__ offs,
                                                  int* __restrict__ bsum, int n) {
  __shared__ int sh[256];
  int t = threadIdx.x;
  int i = blockIdx.x * 256 + t;
  int v = (i < n) ? cnt[i] : 0;
  sh[t] = v; __syncthreads();
  for (int d = 1; d < 256; d <<= 1) {
    int w = (t >= d) ? sh[t - d] : 0;
    __syncthreads();
    sh[t] += w;
    __syncthreads();
  }
  if (i < n) offs[i] = sh[t] - v;
  if (t == 255) bsum[blockIdx.x] = sh[255];
}

__global__ __launch_bounds__(512) void scan_top(int* __restrict__ bsum, int nb) {
  __shared__ int sh[512];
  int t = threadIdx.x;
  int v = (t < nb) ? bsum[t] : 0;
  sh[t] = v; __syncthreads();
  for (int d = 1; d < 512; d <<= 1) {
    int w = (t >= d) ? sh[t - d] : 0;
    __syncthreads();
    sh[t] += w;
    __syncthreads();
  }
  if (t < nb) bsum[t] = sh[t] - v;
}

__global__ __launch_bounds__(256) void scan_add(int* __restrict__ offs,
                                                const int* __restrict__ bsum, int n, int E) {
  int i = blockIdx.x * 256 + threadIdx.x;
  if (i < n) offs[i] += bsum[i >> 8];
  if (i == n) offs[n] = E;
}

__global__ __launch_bounds__(256) void bucket_place(const unsigned int* __restrict__ sorted,
                                                    const int* __restrict__ boffs,
                                                    const int* __restrict__ offs,
                                                    int* __restrict__ ssrc, int N) {
  __shared__ int offl[256];
  __shared__ int cur[256];
  int b = blockIdx.x, t = threadIdx.x;
  int d = b * 256 + t;
  offl[t] = (d < N) ? offs[d] : 0;
  cur[t] = 0;
  __syncthreads();
  int beg = boffs[b], end = boffs[b + 1];
  for (int p = beg + t; p < end; p += 256) {
    unsigned int pk = sorted[p];
    int dl = pk & 255u;
    int r = atomicAdd(&cur[dl], 1);
    ssrc[offl[dl] + r] = (int)(pk >> 8);
  }
}

// ============================ GEMM (K=128) -> int8 rows + per-row scale ============
template <int COLS, bool ABF16>
__global__ __launch_bounds__(256) void gemm_k128(const void* __restrict__ Av,
                                                 const void* __restrict__ Wv,
                                                 unsigned int* __restrict__ Cq,
                                                 float* __restrict__ scl,
                                                 int nrows) {
  constexpr int TN = COLS / 16;
  __shared__ float xs[16][132];
  __shared__ float wsd[16][COLS];
  const int t = threadIdx.x;
  const int ty = t >> 4, tx = t & 15;
  const int row0 = blockIdx.x * 128;
  float acc[8][TN] = {};

  const int r = t >> 1, hf = t & 1;
  const int grow = row0 + r;

  for (int k0 = 0; k0 < 128; k0 += 16) {
    float av[8];
    if (grow < nrows) {
      if constexpr (ABF16) {
        const unsigned short* ap = (const unsigned short*)Av + (size_t)grow * 128 + k0 + hf * 8;
        uint4 u = *(const uint4*)ap;
        av[0] = bf2f(u.x & 0xffffu); av[1] = bf2f(u.x >> 16);
        av[2] = bf2f(u.y & 0xffffu); av[3] = bf2f(u.y >> 16);
        av[4] = bf2f(u.z & 0xffffu); av[5] = bf2f(u.z >> 16);
        av[6] = bf2f(u.w & 0xffffu); av[7] = bf2f(u.w >> 16);
      } else {
        const float* ap = (const float*)Av + (size_t)grow * 128 + k0 + hf * 8;
        float4 f0 = *(const float4*)ap;
        float4 f1 = *(const float4*)(ap + 4);
        av[0] = f0.x; av[1] = f0.y; av[2] = f0.z; av[3] = f0.w;
        av[4] = f1.x; av[5] = f1.y; av[6] = f1.z; av[7] = f1.w;
      }
    } else {
      #pragma unroll
      for (int j = 0; j < 8; j++) av[j] = 0.f;
    }
    #pragma unroll
    for (int j = 0; j < 8; j++) xs[hf * 8 + j][r] = av[j];

    if constexpr (COLS == 128) {
      const float* wp = (const float*)Wv + (size_t)(k0 + ty) * 128 + tx * 8;
      float4 f0 = *(const float4*)wp;
      float4 f1 = *(const float4*)(wp + 4);
      wsd[ty][tx * 8 + 0] = f0.x; wsd[ty][tx * 8 + 1] = f0.y;
      wsd[ty][tx * 8 + 2] = f0.z; wsd[ty][tx * 8 + 3] = f0.w;
      wsd[ty][tx * 8 + 4] = f1.x; wsd[ty][tx * 8 + 5] = f1.y;
      wsd[ty][tx * 8 + 6] = f1.z; wsd[ty][tx * 8 + 7] = f1.w;
    } else {
      const int kk = t >> 4, c = (t & 15) * 4;
      const float* wp = (const float*)Wv + (size_t)(k0 + kk) * 64 + c;
      float4 f0 = *(const float4*)wp;
      wsd[kk][c + 0] = f0.x; wsd[kk][c + 1] = f0.y; wsd[kk][c + 2] = f0.z; wsd[kk][c + 3] = f0.w;
    }
    __syncthreads();

    #pragma unroll
    for (int kk = 0; kk < 16; kk++) {
      float a[8];
      #pragma unroll
      for (int i = 0; i < 8; i++) a[i] = xs[kk][ty * 8 + i];
      float b[TN];
      if constexpr (COLS == 128) {
        #pragma unroll
        for (int j = 0; j < 4; j++) { b[j] = wsd[kk][tx * 4 + j]; b[4 + j] = wsd[kk][64 + tx * 4 + j]; }
      } else {
        #pragma unroll
        for (int j = 0; j < TN; j++) b[j] = wsd[kk][tx * 4 + j];
      }
      #pragma unroll
      for (int i = 0; i < 8; i++)
        #pragma unroll
        for (int j = 0; j < TN; j++) acc[i][j] += a[i] * b[j];
    }
    __syncthreads();
  }

  // ---- epilogue: per-row absmax (shfl over the 16 tx lanes), quantize int8 ----
  #pragma unroll
  for (int i = 0; i < 8; i++) {
    float mx = 0.f;
    #pragma unroll
    for (int j = 0; j < TN; j++) mx = fmaxf(mx, fabsf(acc[i][j]));
    mx = fmaxf(mx, __shfl_xor(mx, 1));
    mx = fmaxf(mx, __shfl_xor(mx, 2));
    mx = fmaxf(mx, __shfl_xor(mx, 4));
    mx = fmaxf(mx, __shfl_xor(mx, 8));
    float inv = mx > 0.f ? 127.f / mx : 0.f;
    int rr = row0 + ty * 8 + i;
    if (rr < nrows) {
      if constexpr (COLS == 128) {
        unsigned int lo = q8(acc[i][0], inv) | (q8(acc[i][1], inv) << 8) |
                          (q8(acc[i][2], inv) << 16) | (q8(acc[i][3], inv) << 24);
        unsigned int hi = q8(acc[i][4], inv) | (q8(acc[i][5], inv) << 8) |
                          (q8(acc[i][6], inv) << 16) | (q8(acc[i][7], inv) << 24);
        Cq[(size_t)rr * 32 + tx] = lo;        // ch tx*4..+3
        Cq[(size_t)rr * 32 + 16 + tx] = hi;   // ch 64+tx*4..+3
      } else {
        unsigned int lo = q8(acc[i][0], inv) | (q8(acc[i][1], inv) << 8) |
                          (q8(acc[i][2], inv) << 16) | (q8(acc[i][3], inv) << 24);
        Cq[(size_t)rr * 16 + tx] = lo;        // ch tx*4..+3
      }
      if (tx == 0) scl[rr] = mx * (1.f / 127.f);
    }
  }
}

// ============================ attention logits (int8 in) ============================
template <int H>
__global__ __launch_bounds__(256) void attn_logits(const void* __restrict__ hq,
                                                   const float* __restrict__ scl,
                                                   const float* __restrict__ att_s,
                                                   const float* __restrict__ att_d,
                                                   float* __restrict__ asrc,
                                                   float* __restrict__ adst, int n) {
  int node = (int)((blockIdx.x * (unsigned)blockDim.x + threadIdx.x) >> 6);
  int lane = threadIdx.x & 63;
  if (node >= n) return;
  float sv = scl[node];
  float ss, sd;
  if constexpr (H == 2) {
    unsigned short v = ((const unsigned short*)hq)[(size_t)node * 64 + lane];  // ch 2l,2l+1
    float hv0 = (float)(int)(signed char)(v & 255);
    float hv1 = (float)(int)(signed char)(v >> 8);
    int ch = lane * 2;
    ss = hv0 * att_s[ch] + hv1 * att_s[ch + 1];
    sd = hv0 * att_d[ch] + hv1 * att_d[ch + 1];
  } else {
    float hv = (float)(int)((const signed char*)hq)[(size_t)node * 64 + lane];
    ss = hv * att_s[lane];
    sd = hv * att_d[lane];
  }
  #pragma unroll
  for (int d = (H == 1 ? 32 : 16); d >= 1; d >>= 1) {
    ss += __shfl_xor(ss, d);
    sd += __shfl_xor(sd, d);
  }
  int gl = (H == 2) ? (lane & 31) : lane;
  int hd = (H == 2) ? (lane >> 5) : 0;
  if (gl == 0) {
    asrc[(size_t)node * H + hd] = ss * sv;
    adst[(size_t)node * H + hd] = sd * sv;
  }
}

// ============= softmax-aggregate: batched flash-style, int8 rows =============
// Per-row scale folded into p AFTER the denominator is formed (softmax exact).
template <int H, bool ELU_OUT, bool F32OUT>
__global__ __launch_bounds__(256) void agg_gather(const void* __restrict__ hq,
                                                  const float* __restrict__ scl,
                                                  const float* __restrict__ asrc,
                                                  const float* __restrict__ adst,
                                                  const int* __restrict__ offs,
                                                  const int* __restrict__ ssrc,
                                                  const float* __restrict__ bias,
                                                  void* __restrict__ outv, int n) {
  int node = (int)((blockIdx.x * (unsigned)blockDim.x + threadIdx.x) >> 6);
  int lane = threadIdx.x & 63;
  if (node >= n) return;
  const int hd = lane >> 5;
  const int beg = offs[node], end = offs[node + 1];

  float adh, m, acc0, acc1, d;
  const float s_self = scl[node];
  if constexpr (H == 2) {
    float2 adv = ((const float2*)adst)[node];
    float2 asv = ((const float2*)asrc)[node];
    adh = hd ? adv.y : adv.x;
    m = lrelu02((hd ? asv.y : asv.x) + adh);  // e_self per head
    unsigned short v = ((const unsigned short*)hq)[((size_t)node << 6) + lane];  // ch 2l,2l+1
    acc0 = s_self * (float)(int)(signed char)(v & 255);  // p_self = 1
    acc1 = s_self * (float)(int)(signed char)(v >> 8);
  } else {
    adh = adst[node];
    m = lrelu02(asrc[node] + adh);
    if (hd == 0) {
      unsigned short v = ((const unsigned short*)hq)[((size_t)node << 5) + lane];
      acc0 = s_self * (float)(int)(signed char)(v & 255);
      acc1 = s_self * (float)(int)(signed char)(v >> 8);
    } else {
      acc0 = 0.f; acc1 = 0.f;
    }
  }
  d = 1.f;  // p_self

  constexpr int CH = (H == 2) ? 32 : 64;
  for (int pos = beg; pos < end; pos += CH) {
    const int len = min(CH, end - pos);
    int li = (H == 2) ? (lane & 31) : lane;
    bool valid = li < len;
    int s_l = valid ? ssrc[pos + li] : 0;
    float scl_l = valid ? scl[s_l] : 0.f;
    float e_l;
    if constexpr (H == 2) {
      float a = asrc[(s_l << 1) + hd];
      e_l = valid ? lrelu02(a + adh) : NEG_INF;
    } else {
      float a = asrc[s_l];
      e_l = valid ? lrelu02(a + adh) : NEG_INF;
    }
    float mc = e_l;
    #pragma unroll
    for (int dlt = CH >> 1; dlt >= 1; dlt >>= 1) mc = fmaxf(mc, __shfl_xor(mc, dlt));
    float m_new = fmaxf(m, mc);
    float f = __expf(m - m_new);
    float p_l = __expf(e_l - m_new);  // 0 for invalid lanes
    float sc = p_l;
    #pragma unroll
    for (int dlt = CH >> 1; dlt >= 1; dlt >>= 1) sc += __shfl_xor(sc, dlt);
    d = d * f + sc;
    acc0 *= f; acc1 *= f;
    m = m_new;
    p_l *= scl_l;  // fold per-row dequant scale into the weight (post-denominator)

    if constexpr (H == 2) {
      #pragma unroll 8
      for (int j = 0; j < len; j++) {
        int s = rl_i(s_l, j);
        float pa = rl_f(p_l, j);
        float pb = rl_f(p_l, j + 32);
        float p = hd ? pb : pa;
        unsigned short v = ((const unsigned short*)hq)[((size_t)(unsigned)s << 6) + lane];
        acc0 += p * (float)(int)(signed char)(v & 255);
        acc1 += p * (float)(int)(signed char)(v >> 8);
      }
    } else {
      const int npair = (len + 1) >> 1;
      #pragma unroll 8
      for (int i = 0; i < npair; i++) {
        int jj = 2 * i;
        int s0 = rl_i(s_l, jj), s1 = rl_i(s_l, jj + 1);
        float p0 = rl_f(p_l, jj), p1 = rl_f(p_l, jj + 1);  // p=0 past len
        int s = hd ? s1 : s0;
        float p = hd ? p1 : p0;
        unsigned short v = ((const unsigned short*)hq)[((size_t)(unsigned)s << 5) + (lane & 31)];
        acc0 += p * (float)(int)(signed char)(v & 255);
        acc1 += p * (float)(int)(signed char)(v >> 8);
      }
    }
  }

  if constexpr (H == 1) {  // halves accumulated different edges
    acc0 += __shfl_xor(acc0, 32);
    acc1 += __shfl_xor(acc1, 32);
  }

  const float inv = 1.f / d;
  if constexpr (H == 2) {
    float2 bv = ((const float2*)bias)[lane];
    float v0 = acc0 * inv + bv.x;
    float v1 = acc1 * inv + bv.y;
    if (ELU_OUT) {
      v0 = v0 > 0.f ? v0 : (__expf(v0) - 1.f);
      v1 = v1 > 0.f ? v1 : (__expf(v1) - 1.f);
    }
    if constexpr (F32OUT) {
      ((float2*)outv)[(size_t)node * 64 + lane] = make_float2(v0, v1);
    } else {
      unsigned int pk = (unsigned int)f2bf(v0) | ((unsigned int)f2bf(v1) << 16);
      ((unsigned int*)outv)[(size_t)node * 64 + lane] = pk;
    }
  } else {
    if (hd == 0) {
      float2 bv = ((const float2*)bias)[lane];
      float v0 = acc0 * inv + bv.x;
      float v1 = acc1 * inv + bv.y;
      if (ELU_OUT) {
        v0 = v0 > 0.f ? v0 : (__expf(v0) - 1.f);
        v1 = v1 > 0.f ? v1 : (__expf(v1) - 1.f);
      }
      if constexpr (F32OUT) {
        ((float2*)outv)[(size_t)node * 32 + lane] = make_float2(v0, v1);
      } else {
        unsigned int pk = (unsigned int)f2bf(v0) | ((unsigned int)f2bf(v1) << 16);
        ((unsigned int*)outv)[(size_t)node * 32 + lane] = pk;
      }
    }
  }
}

// ============================ launch ============================
extern "C" void kernel_launch(void* const* d_in, const int* in_sizes, int n_in,
                              void* d_out, int out_size, void* d_ws, size_t ws_size,
                              hipStream_t stream) {
  const int N = in_sizes[0] / FIN;      // 100000
  const int E = in_sizes[1] / 2;        // 1600000

  const void*  x   = d_in[0];
  const int*   ei  = (const int*)d_in[1];
  const void*  W1  = d_in[2];
  const float* as1 = (const float*)d_in[3];
  const float* ad1 = (const float*)d_in[4];
  const float* b1  = (const float*)d_in[5];
  const void*  W2  = d_in[6];
  const float* as2 = (const float*)d_in[7];
  const float* ad2 = (const float*)d_in[8];
  const float* b2  = (const float*)d_in[9];

  const int* e_src = ei;
  const int* e_dst = ei + E;

  char* p = (char*)d_ws;
  auto carve = [&](size_t bytes) {
    char* q = p;
    p += (bytes + 255) & ~(size_t)255;
    return (void*)q;
  };
  unsigned int* h1q  = (unsigned int*)carve((size_t)N * 128);      // int8 rows, layer1
  float* scl1        = (float*)carve((size_t)N * 4);
  unsigned int* h2q  = (unsigned int*)carve((size_t)N * 64);       // int8 rows, layer2
  float* scl2        = (float*)carve((size_t)N * 4);
  unsigned short* buf2 = (unsigned short*)carve((size_t)N * HC1 * 2);  // bf16 layer1 out
  float* asrc1 = (float*)carve((size_t)N * 2 * 4);
  float* adst1 = (float*)carve((size_t)N * 2 * 4);
  float* asrc2 = (float*)carve((size_t)N * 4);
  float* adst2 = (float*)carve((size_t)N * 4);
  int* counts  = (int*)carve((size_t)N * 4);
  int* offs    = (int*)carve((size_t)(N + 1) * 4);
  int* bsum    = (int*)carve(512 * 4);
  int* bhist   = (int*)carve((size_t)2 * 512 * 4);  // bhist + gcur, one memset
  int* gcur    = bhist + 512;
  int* boffs   = (int*)carve(513 * 4);
  unsigned int* sorted = (unsigned int*)carve((size_t)E * 4);
  int* ssrc    = (int*)carve((size_t)E * 4);

  const int NB = (N + 255) >> 8;
  const int nb = (N + 255) / 256;
  const int sgrid = (E + EPB - 1) / EPB;
  const int wgrid = (int)(((size_t)N * 64 + 255) / 256);
  const int ggrid = (N + 127) / 128;

  // ---- CSR build (bucket-sorted, shared by both layers) ----
  hipMemsetAsync(bhist, 0, (size_t)2 * 512 * 4, stream);
  bucket_hist<<<sgrid, 256, 0, stream>>>(e_dst, bhist, E, NB);
  scan_buckets<<<1, 512, 0, stream>>>(bhist, boffs, NB);
  bucket_scatter<<<sgrid, 256, 0, stream>>>(e_src, e_dst, boffs, gcur, sorted, E, NB);
  bucket_count<<<NB, 256, 0, stream>>>(sorted, boffs, counts, N);
  scan_block<<<nb, 256, 0, stream>>>(counts, offs, bsum, N);
  scan_top<<<1, 512, 0, stream>>>(bsum, nb);
  scan_add<<<(N + 256) / 256, 256, 0, stream>>>(offs, bsum, N, E);
  bucket_place<<<NB, 256, 0, stream>>>(sorted, boffs, offs, ssrc, N);

  // ---- layer 1 ----
  gemm_k128<128, false><<<ggrid, 256, 0, stream>>>(x, W1, h1q, scl1, N);
  attn_logits<2><<<wgrid, 256, 0, stream>>>(h1q, scl1, as1, ad1, asrc1, adst1, N);
  agg_gather<2, true, false><<<wgrid, 256, 0, stream>>>(h1q, scl1, asrc1, adst1, offs, ssrc,
                                                        b1, buf2, N);

  // ---- layer 2 ----
  gemm_k128<64, true><<<ggrid, 256, 0, stream>>>(buf2, W2, h2q, scl2, N);
  attn_logits<1><<<wgrid, 256, 0, stream>>>(h2q, scl2, as2, ad2, asrc2, adst2, N);
  agg_gather<1, false, true><<<wgrid, 256, 0, stream>>>(h2q, scl2, asrc2, adst2, offs, ssrc,
                                                        b2, d_out, N);
}

// Round 7
// 421.439 us; speedup vs baseline: 1.1335x; 1.1335x over previous
//
#include <hip/hip_runtime.h>
#include <hip/hip_bf16.h>
#include <cstdint>
#include <cstddef>

// Inputs/outputs fp32 (reference dtype). Node features for the gather phase are
// stored int8 with per-row scale. Round-6 evidence: agg_gather pinned at ~118us
// with halved bytes AND fewer instructions -> latency-bound with MLP~1-2
// (VGPR_Count=16). This round: explicit 8-deep load batching in the gather.
static constexpr int FIN = 128;
static constexpr int HC1 = 128;  // layer1: H=2, C=64, concat
static constexpr int EPB = 4096; // edges per block in bucket_scatter

__device__ __forceinline__ float bf2f(unsigned int u) { return __uint_as_float(u << 16); }
__device__ __forceinline__ unsigned short f2bf(float f) {  // round-to-nearest-even
  unsigned int u = __float_as_uint(f);
  return (unsigned short)((u + 0x7fff + ((u >> 16) & 1)) >> 16);
}
__device__ __forceinline__ float lrelu02(float x) { return x > 0.f ? x : 0.2f * x; }
__device__ __forceinline__ int rl_i(int v, int l) { return __builtin_amdgcn_readlane(v, l); }
__device__ __forceinline__ float rl_f(float v, int l) {
  return __int_as_float(__builtin_amdgcn_readlane(__float_as_int(v), l));
}
__device__ __forceinline__ unsigned int q8(float x, float inv) {
  float q = fminf(fmaxf(x * inv, -127.f), 127.f);
  return (unsigned int)((int)rintf(q) & 255);
}
#define NEG_INF __int_as_float(0xff800000)

// ============================ bucket-sorted CSR build ============================
__global__ __launch_bounds__(256) void bucket_hist(const int* __restrict__ dst,
                                                   int* __restrict__ bhist, int E, int NB) {
  __shared__ int lh[512];
  int t = threadIdx.x;
  lh[t] = 0; lh[t + 256] = 0;
  __syncthreads();
  int e0 = blockIdx.x * EPB;
  #pragma unroll
  for (int i = 0; i < EPB / 256; i++) {
    int e = e0 + i * 256 + t;
    if (e < E) atomicAdd(&lh[dst[e] >> 8], 1);
  }
  __syncthreads();
  for (int x = t; x < NB; x += 256) {
    int c = lh[x];
    if (c > 0) atomicAdd(&bhist[x], c);
  }
}

__global__ __launch_bounds__(512) void scan_buckets(const int* __restrict__ bhist,
                                                    int* __restrict__ boffs, int n) {
  __shared__ int sh[512];
  int t = threadIdx.x;
  int v = (t < n) ? bhist[t] : 0;
  sh[t] = v; __syncthreads();
  for (int d = 1; d < 512; d <<= 1) {
    int w = (t >= d) ? sh[t - d] : 0;
    __syncthreads();
    sh[t] += w;
    __syncthreads();
  }
  if (t <= n) boffs[t] = sh[t] - v;
}

__global__ __launch_bounds__(256) void bucket_scatter(const int* __restrict__ src,
                                                      const int* __restrict__ dst,
                                                      const int* __restrict__ boffs,
                                                      int* __restrict__ gcur,
                                                      unsigned int* __restrict__ sorted,
                                                      int E, int NB) {
  __shared__ int lh[512];
  int t = threadIdx.x;
  lh[t] = 0; lh[t + 256] = 0;
  __syncthreads();
  int e0 = blockIdx.x * EPB;
  #pragma unroll
  for (int i = 0; i < EPB / 256; i++) {
    int e = e0 + i * 256 + t;
    if (e < E) atomicAdd(&lh[dst[e] >> 8], 1);
  }
  __syncthreads();
  for (int x = t; x < NB; x += 256) {
    int c = lh[x];
    lh[x] = (c > 0) ? (boffs[x] + atomicAdd(&gcur[x], c)) : 0;
  }
  __syncthreads();
  #pragma unroll
  for (int i = 0; i < EPB / 256; i++) {
    int e = e0 + i * 256 + t;
    if (e < E) {
      int d = dst[e];
      int pos = atomicAdd(&lh[d >> 8], 1);
      sorted[pos] = ((unsigned int)src[e] << 8) | (unsigned int)(d & 255);
    }
  }
}

__global__ __launch_bounds__(256) void bucket_count(const unsigned int* __restrict__ sorted,
                                                    const int* __restrict__ boffs,
                                                    int* __restrict__ counts, int N) {
  __shared__ int cnt[256];
  int b = blockIdx.x, t = threadIdx.x;
  cnt[t] = 0; __syncthreads();
  int beg = boffs[b], end = boffs[b + 1];
  for (int p = beg + t; p < end; p += 256)
    atomicAdd(&cnt[sorted[p] & 255u], 1);
  __syncthreads();
  int d = b * 256 + t;
  if (d < N) counts[d] = cnt[t];
}

__global__ __launch_bounds__(256) void scan_block(const int* __restrict__ cnt,
                                                  int* __restrict__ offs,
                                                  int* __restrict__ bsum, int n) {
  __shared__ int sh[256];
  int t = threadIdx.x;
  int i = blockIdx.x * 256 + t;
  int v = (i < n) ? cnt[i] : 0;
  sh[t] = v; __syncthreads();
  for (int d = 1; d < 256; d <<= 1) {
    int w = (t >= d) ? sh[t - d] : 0;
    __syncthreads();
    sh[t] += w;
    __syncthreads();
  }
  if (i < n) offs[i] = sh[t] - v;
  if (t == 255) bsum[blockIdx.x] = sh[255];
}

__global__ __launch_bounds__(512) void scan_top(int* __restrict__ bsum, int nb) {
  __shared__ int sh[512];
  int t = threadIdx.x;
  int v = (t < nb) ? bsum[t] : 0;
  sh[t] = v; __syncthreads();
  for (int d = 1; d < 512; d <<= 1) {
    int w = (t >= d) ? sh[t - d] : 0;
    __syncthreads();
    sh[t] += w;
    __syncthreads();
  }
  if (t < nb) bsum[t] = sh[t] - v;
}

__global__ __launch_bounds__(256) void scan_add(int* __restrict__ offs,
                                                const int* __restrict__ bsum, int n, int E) {
  int i = blockIdx.x * 256 + threadIdx.x;
  if (i < n) offs[i] += bsum[i >> 8];
  if (i == n) offs[n] = E;
}

__global__ __launch_bounds__(256) void bucket_place(const unsigned int* __restrict__ sorted,
                                                    const int* __restrict__ boffs,
                                                    const int* __restrict__ offs,
                                                    int* __restrict__ ssrc, int N) {
  __shared__ int offl[256];
  __shared__ int cur[256];
  int b = blockIdx.x, t = threadIdx.x;
  int d = b * 256 + t;
  offl[t] = (d < N) ? offs[d] : 0;
  cur[t] = 0;
  __syncthreads();
  int beg = boffs[b], end = boffs[b + 1];
  for (int p = beg + t; p < end; p += 256) {
    unsigned int pk = sorted[p];
    int dl = pk & 255u;
    int r = atomicAdd(&cur[dl], 1);
    ssrc[offl[dl] + r] = (int)(pk >> 8);
  }
}

// ============================ GEMM (K=128) -> int8 rows + per-row scale ============
template <int COLS, bool ABF16>
__global__ __launch_bounds__(256) void gemm_k128(const void* __restrict__ Av,
                                                 const void* __restrict__ Wv,
                                                 unsigned int* __restrict__ Cq,
                                                 float* __restrict__ scl,
                                                 int nrows) {
  constexpr int TN = COLS / 16;
  __shared__ float xs[16][132];
  __shared__ float wsd[16][COLS];
  const int t = threadIdx.x;
  const int ty = t >> 4, tx = t & 15;
  const int row0 = blockIdx.x * 128;
  float acc[8][TN] = {};

  const int r = t >> 1, hf = t & 1;
  const int grow = row0 + r;

  for (int k0 = 0; k0 < 128; k0 += 16) {
    float av[8];
    if (grow < nrows) {
      if constexpr (ABF16) {
        const unsigned short* ap = (const unsigned short*)Av + (size_t)grow * 128 + k0 + hf * 8;
        uint4 u = *(const uint4*)ap;
        av[0] = bf2f(u.x & 0xffffu); av[1] = bf2f(u.x >> 16);
        av[2] = bf2f(u.y & 0xffffu); av[3] = bf2f(u.y >> 16);
        av[4] = bf2f(u.z & 0xffffu); av[5] = bf2f(u.z >> 16);
        av[6] = bf2f(u.w & 0xffffu); av[7] = bf2f(u.w >> 16);
      } else {
        const float* ap = (const float*)Av + (size_t)grow * 128 + k0 + hf * 8;
        float4 f0 = *(const float4*)ap;
        float4 f1 = *(const float4*)(ap + 4);
        av[0] = f0.x; av[1] = f0.y; av[2] = f0.z; av[3] = f0.w;
        av[4] = f1.x; av[5] = f1.y; av[6] = f1.z; av[7] = f1.w;
      }
    } else {
      #pragma unroll
      for (int j = 0; j < 8; j++) av[j] = 0.f;
    }
    #pragma unroll
    for (int j = 0; j < 8; j++) xs[hf * 8 + j][r] = av[j];

    if constexpr (COLS == 128) {
      const float* wp = (const float*)Wv + (size_t)(k0 + ty) * 128 + tx * 8;
      float4 f0 = *(const float4*)wp;
      float4 f1 = *(const float4*)(wp + 4);
      wsd[ty][tx * 8 + 0] = f0.x; wsd[ty][tx * 8 + 1] = f0.y;
      wsd[ty][tx * 8 + 2] = f0.z; wsd[ty][tx * 8 + 3] = f0.w;
      wsd[ty][tx * 8 + 4] = f1.x; wsd[ty][tx * 8 + 5] = f1.y;
      wsd[ty][tx * 8 + 6] = f1.z; wsd[ty][tx * 8 + 7] = f1.w;
    } else {
      const int kk = t >> 4, c = (t & 15) * 4;
      const float* wp = (const float*)Wv + (size_t)(k0 + kk) * 64 + c;
      float4 f0 = *(const float4*)wp;
      wsd[kk][c + 0] = f0.x; wsd[kk][c + 1] = f0.y; wsd[kk][c + 2] = f0.z; wsd[kk][c + 3] = f0.w;
    }
    __syncthreads();

    #pragma unroll
    for (int kk = 0; kk < 16; kk++) {
      float a[8];
      #pragma unroll
      for (int i = 0; i < 8; i++) a[i] = xs[kk][ty * 8 + i];
      float b[TN];
      if constexpr (COLS == 128) {
        #pragma unroll
        for (int j = 0; j < 4; j++) { b[j] = wsd[kk][tx * 4 + j]; b[4 + j] = wsd[kk][64 + tx * 4 + j]; }
      } else {
        #pragma unroll
        for (int j = 0; j < TN; j++) b[j] = wsd[kk][tx * 4 + j];
      }
      #pragma unroll
      for (int i = 0; i < 8; i++)
        #pragma unroll
        for (int j = 0; j < TN; j++) acc[i][j] += a[i] * b[j];
    }
    __syncthreads();
  }

  // ---- epilogue: per-row absmax (shfl over the 16 tx lanes), quantize int8 ----
  #pragma unroll
  for (int i = 0; i < 8; i++) {
    float mx = 0.f;
    #pragma unroll
    for (int j = 0; j < TN; j++) mx = fmaxf(mx, fabsf(acc[i][j]));
    mx = fmaxf(mx, __shfl_xor(mx, 1));
    mx = fmaxf(mx, __shfl_xor(mx, 2));
    mx = fmaxf(mx, __shfl_xor(mx, 4));
    mx = fmaxf(mx, __shfl_xor(mx, 8));
    float inv = mx > 0.f ? 127.f / mx : 0.f;
    int rr = row0 + ty * 8 + i;
    if (rr < nrows) {
      if constexpr (COLS == 128) {
        unsigned int lo = q8(acc[i][0], inv) | (q8(acc[i][1], inv) << 8) |
                          (q8(acc[i][2], inv) << 16) | (q8(acc[i][3], inv) << 24);
        unsigned int hi = q8(acc[i][4], inv) | (q8(acc[i][5], inv) << 8) |
                          (q8(acc[i][6], inv) << 16) | (q8(acc[i][7], inv) << 24);
        Cq[(size_t)rr * 32 + tx] = lo;        // ch tx*4..+3
        Cq[(size_t)rr * 32 + 16 + tx] = hi;   // ch 64+tx*4..+3
      } else {
        unsigned int lo = q8(acc[i][0], inv) | (q8(acc[i][1], inv) << 8) |
                          (q8(acc[i][2], inv) << 16) | (q8(acc[i][3], inv) << 24);
        Cq[(size_t)rr * 16 + tx] = lo;        // ch tx*4..+3
      }
      if (tx == 0) scl[rr] = mx * (1.f / 127.f);
    }
  }
}

// ============================ attention logits (int8 in) ============================
template <int H>
__global__ __launch_bounds__(256) void attn_logits(const void* __restrict__ hq,
                                                   const float* __restrict__ scl,
                                                   const float* __restrict__ att_s,
                                                   const float* __restrict__ att_d,
                                                   float* __restrict__ asrc,
                                                   float* __restrict__ adst, int n) {
  int node = (int)((blockIdx.x * (unsigned)blockDim.x + threadIdx.x) >> 6);
  int lane = threadIdx.x & 63;
  if (node >= n) return;
  float sv = scl[node];
  float ss, sd;
  if constexpr (H == 2) {
    unsigned short v = ((const unsigned short*)hq)[(size_t)node * 64 + lane];  // ch 2l,2l+1
    float hv0 = (float)(int)(signed char)(v & 255);
    float hv1 = (float)(int)(signed char)(v >> 8);
    int ch = lane * 2;
    ss = hv0 * att_s[ch] + hv1 * att_s[ch + 1];
    sd = hv0 * att_d[ch] + hv1 * att_d[ch + 1];
  } else {
    float hv = (float)(int)((const signed char*)hq)[(size_t)node * 64 + lane];
    ss = hv * att_s[lane];
    sd = hv * att_d[lane];
  }
  #pragma unroll
  for (int d = (H == 1 ? 32 : 16); d >= 1; d >>= 1) {
    ss += __shfl_xor(ss, d);
    sd += __shfl_xor(sd, d);
  }
  int gl = (H == 2) ? (lane & 31) : lane;
  int hd = (H == 2) ? (lane >> 5) : 0;
  if (gl == 0) {
    asrc[(size_t)node * H + hd] = ss * sv;
    adst[(size_t)node * H + hd] = sd * sv;
  }
}

// ============= softmax-aggregate: batched flash-style, int8 rows, 8-deep MLP =========
// Inner gather: groups of 8 independent loads into a register array (phase 1),
// then dequant+FMA (phase 2). Invalid-slot padding: s=0, p=0 -> branch-free.
template <int H, bool ELU_OUT, bool F32OUT>
__global__ __launch_bounds__(256) void agg_gather(const void* __restrict__ hq,
                                                  const float* __restrict__ scl,
                                                  const float* __restrict__ asrc,
                                                  const float* __restrict__ adst,
                                                  const int* __restrict__ offs,
                                                  const int* __restrict__ ssrc,
                                                  const float* __restrict__ bias,
                                                  void* __restrict__ outv, int n) {
  int node = (int)((blockIdx.x * (unsigned)blockDim.x + threadIdx.x) >> 6);
  int lane = threadIdx.x & 63;
  if (node >= n) return;
  const int hd = lane >> 5;
  const int beg = offs[node], end = offs[node + 1];
  const unsigned short* hq16 = (const unsigned short*)hq;

  float adh, m, acc0, acc1, d;
  const float s_self = scl[node];
  if constexpr (H == 2) {
    float2 adv = ((const float2*)adst)[node];
    float2 asv = ((const float2*)asrc)[node];
    adh = hd ? adv.y : adv.x;
    m = lrelu02((hd ? asv.y : asv.x) + adh);  // e_self per head
    unsigned short v = hq16[((size_t)node << 6) + lane];  // ch 2l,2l+1
    acc0 = s_self * (float)(int)(signed char)(v & 255);  // p_self = 1
    acc1 = s_self * (float)(int)(signed char)(v >> 8);
  } else {
    adh = adst[node];
    m = lrelu02(asrc[node] + adh);
    if (hd == 0) {
      unsigned short v = hq16[((size_t)node << 5) + lane];
      acc0 = s_self * (float)(int)(signed char)(v & 255);
      acc1 = s_self * (float)(int)(signed char)(v >> 8);
    } else {
      acc0 = 0.f; acc1 = 0.f;
    }
  }
  d = 1.f;  // p_self

  constexpr int CH = (H == 2) ? 32 : 64;
  for (int pos = beg; pos < end; pos += CH) {
    const int len = min(CH, end - pos);
    int li = (H == 2) ? (lane & 31) : lane;
    bool valid = li < len;
    int s_l = valid ? ssrc[pos + li] : 0;      // pad: node 0 (safe), p will be 0
    float scl_l = valid ? scl[s_l] : 0.f;
    float e_l;
    if constexpr (H == 2) {
      float a = asrc[(s_l << 1) + hd];
      e_l = valid ? lrelu02(a + adh) : NEG_INF;
    } else {
      float a = asrc[s_l];
      e_l = valid ? lrelu02(a + adh) : NEG_INF;
    }
    float mc = e_l;
    #pragma unroll
    for (int dlt = CH >> 1; dlt >= 1; dlt >>= 1) mc = fmaxf(mc, __shfl_xor(mc, dlt));
    float m_new = fmaxf(m, mc);
    float f = __expf(m - m_new);
    float p_l = __expf(e_l - m_new);  // 0 for invalid lanes
    float sc = p_l;
    #pragma unroll
    for (int dlt = CH >> 1; dlt >= 1; dlt >>= 1) sc += __shfl_xor(sc, dlt);
    d = d * f + sc;
    acc0 *= f; acc1 *= f;
    m = m_new;
    p_l *= scl_l;  // fold per-row dequant scale into the weight (post-denominator)

    if constexpr (H == 2) {
      // groups of 8 edges; all-lane row loads batched for 8-deep MLP
      const int ng = (len + 7) >> 3;
      for (int g = 0; g < ng; g++) {
        const int jb = g * 8;  // wave-uniform
        unsigned short v[8];
        #pragma unroll
        for (int k = 0; k < 8; k++) {
          int s = rl_i(s_l, jb + k);  // jb+k <= 31 always (len<=32, ng<=4)
          v[k] = hq16[((size_t)(unsigned)s << 6) + lane];
        }
        #pragma unroll
        for (int k = 0; k < 8; k++) {
          float pa = rl_f(p_l, jb + k);
          float pb = rl_f(p_l, jb + k + 32);
          float p = hd ? pb : pa;   // 0 for padded slots
          acc0 += p * (float)(int)(signed char)(v[k] & 255);
          acc1 += p * (float)(int)(signed char)(v[k] >> 8);
        }
      }
    } else {
      // pairs of edges (two 64B rows fill the wave); groups of 8 pairs
      const int npair = (len + 1) >> 1;
      const int ng = (npair + 7) >> 3;
      for (int g = 0; g < ng; g++) {
        const int jb = g * 16;  // edge base, wave-uniform
        unsigned short v[8];
        #pragma unroll
        for (int k = 0; k < 8; k++) {
          int jj = jb + 2 * k;            // jj+1 <= 63 always (len<=64, ng<=4)
          int s0 = rl_i(s_l, jj), s1 = rl_i(s_l, jj + 1);
          int s = hd ? s1 : s0;
          v[k] = hq16[((size_t)(unsigned)s << 5) + (lane & 31)];
        }
        #pragma unroll
        for (int k = 0; k < 8; k++) {
          int jj = jb + 2 * k;
          float p0 = rl_f(p_l, jj), p1 = rl_f(p_l, jj + 1);
          float p = hd ? p1 : p0;  // 0 for padded slots
          acc0 += p * (float)(int)(signed char)(v[k] & 255);
          acc1 += p * (float)(int)(signed char)(v[k] >> 8);
        }
      }
    }
  }

  if constexpr (H == 1) {  // halves accumulated different edges
    acc0 += __shfl_xor(acc0, 32);
    acc1 += __shfl_xor(acc1, 32);
  }

  const float inv = 1.f / d;
  if constexpr (H == 2) {
    float2 bv = ((const float2*)bias)[lane];
    float v0 = acc0 * inv + bv.x;
    float v1 = acc1 * inv + bv.y;
    if (ELU_OUT) {
      v0 = v0 > 0.f ? v0 : (__expf(v0) - 1.f);
      v1 = v1 > 0.f ? v1 : (__expf(v1) - 1.f);
    }
    if constexpr (F32OUT) {
      ((float2*)outv)[(size_t)node * 64 + lane] = make_float2(v0, v1);
    } else {
      unsigned int pk = (unsigned int)f2bf(v0) | ((unsigned int)f2bf(v1) << 16);
      ((unsigned int*)outv)[(size_t)node * 64 + lane] = pk;
    }
  } else {
    if (hd == 0) {
      float2 bv = ((const float2*)bias)[lane];
      float v0 = acc0 * inv + bv.x;
      float v1 = acc1 * inv + bv.y;
      if (ELU_OUT) {
        v0 = v0 > 0.f ? v0 : (__expf(v0) - 1.f);
        v1 = v1 > 0.f ? v1 : (__expf(v1) - 1.f);
      }
      if constexpr (F32OUT) {
        ((float2*)outv)[(size_t)node * 32 + lane] = make_float2(v0, v1);
      } else {
        unsigned int pk = (unsigned int)f2bf(v0) | ((unsigned int)f2bf(v1) << 16);
        ((unsigned int*)outv)[(size_t)node * 32 + lane] = pk;
      }
    }
  }
}

// ============================ launch ============================
extern "C" void kernel_launch(void* const* d_in, const int* in_sizes, int n_in,
                              void* d_out, int out_size, void* d_ws, size_t ws_size,
                              hipStream_t stream) {
  const int N = in_sizes[0] / FIN;      // 100000
  const int E = in_sizes[1] / 2;        // 1600000

  const void*  x   = d_in[0];
  const int*   ei  = (const int*)d_in[1];
  const void*  W1  = d_in[2];
  const float* as1 = (const float*)d_in[3];
  const float* ad1 = (const float*)d_in[4];
  const float* b1  = (const float*)d_in[5];
  const void*  W2  = d_in[6];
  const float* as2 = (const float*)d_in[7];
  const float* ad2 = (const float*)d_in[8];
  const float* b2  = (const float*)d_in[9];

  const int* e_src = ei;
  const int* e_dst = ei + E;

  char* p = (char*)d_ws;
  auto carve = [&](size_t bytes) {
    char* q = p;
    p += (bytes + 255) & ~(size_t)255;
    return (void*)q;
  };
  unsigned int* h1q  = (unsigned int*)carve((size_t)N * 128);      // int8 rows, layer1
  float* scl1        = (float*)carve((size_t)N * 4);
  unsigned int* h2q  = (unsigned int*)carve((size_t)N * 64);       // int8 rows, layer2
  float* scl2        = (float*)carve((size_t)N * 4);
  unsigned short* buf2 = (unsigned short*)carve((size_t)N * HC1 * 2);  // bf16 layer1 out
  float* asrc1 = (float*)carve((size_t)N * 2 * 4);
  float* adst1 = (float*)carve((size_t)N * 2 * 4);
  float* asrc2 = (float*)carve((size_t)N * 4);
  float* adst2 = (float*)carve((size_t)N * 4);
  int* counts  = (int*)carve((size_t)N * 4);
  int* offs    = (int*)carve((size_t)(N + 1) * 4);
  int* bsum    = (int*)carve(512 * 4);
  int* bhist   = (int*)carve((size_t)2 * 512 * 4);  // bhist + gcur, one memset
  int* gcur    = bhist + 512;
  int* boffs   = (int*)carve(513 * 4);
  unsigned int* sorted = (unsigned int*)carve((size_t)E * 4);
  int* ssrc    = (int*)carve((size_t)E * 4);

  const int NB = (N + 255) >> 8;
  const int nb = (N + 255) / 256;
  const int sgrid = (E + EPB - 1) / EPB;
  const int wgrid = (int)(((size_t)N * 64 + 255) / 256);
  const int ggrid = (N + 127) / 128;

  // ---- CSR build (bucket-sorted, shared by both layers) ----
  hipMemsetAsync(bhist, 0, (size_t)2 * 512 * 4, stream);
  bucket_hist<<<sgrid, 256, 0, stream>>>(e_dst, bhist, E, NB);
  scan_buckets<<<1, 512, 0, stream>>>(bhist, boffs, NB);
  bucket_scatter<<<sgrid, 256, 0, stream>>>(e_src, e_dst, boffs, gcur, sorted, E, NB);
  bucket_count<<<NB, 256, 0, stream>>>(sorted, boffs, counts, N);
  scan_block<<<nb, 256, 0, stream>>>(counts, offs, bsum, N);
  scan_top<<<1, 512, 0, stream>>>(bsum, nb);
  scan_add<<<(N + 256) / 256, 256, 0, stream>>>(offs, bsum, N, E);
  bucket_place<<<NB, 256, 0, stream>>>(sorted, boffs, offs, ssrc, N);

  // ---- layer 1 ----
  gemm_k128<128, false><<<ggrid, 256, 0, stream>>>(x, W1, h1q, scl1, N);
  attn_logits<2><<<wgrid, 256, 0, stream>>>(h1q, scl1, as1, ad1, asrc1, adst1, N);
  agg_gather<2, true, false><<<wgrid, 256, 0, stream>>>(h1q, scl1, asrc1, adst1, offs, ssrc,
                                                        b1, buf2, N);

  // ---- layer 2 ----
  gemm_k128<64, true><<<ggrid, 256, 0, stream>>>(buf2, W2, h2q, scl2, N);
  attn_logits<1><<<wgrid, 256, 0, stream>>>(h2q, scl2, as2, ad2, asrc2, adst2, N);
  agg_gather<1, false, true><<<wgrid, 256, 0, stream>>>(h2q, scl2, asrc2, adst2, offs, ssrc,
                                                        b2, d_out, N);
}

// Round 8
// 403.827 us; speedup vs baseline: 1.1829x; 1.0436x over previous
//
#include <hip/hip_runtime.h>
#include <hip/hip_bf16.h>
#include <cstdint>
#include <cstddef>

// Inputs/outputs fp32 (reference dtype). Node features stored as BIASED uint8
// (q+128) with per-row scale; bias removed analytically via SPF = sum of folded
// softmax weights (round-7 evidence: agg_gather is VALU-issue-bound at 86%;
// this round moves p-broadcast to LDS (LGKM pipe) and dequant to cvt_f32_ubyte).
static constexpr int FIN = 128;
static constexpr int HC1 = 128;  // layer1: H=2, C=64, concat
static constexpr int EPB = 4096; // edges per block in bucket_scatter

__device__ __forceinline__ float bf2f(unsigned int u) { return __uint_as_float(u << 16); }
__device__ __forceinline__ unsigned short f2bf(float f) {  // round-to-nearest-even
  unsigned int u = __float_as_uint(f);
  return (unsigned short)((u + 0x7fff + ((u >> 16) & 1)) >> 16);
}
__device__ __forceinline__ float lrelu02(float x) { return x > 0.f ? x : 0.2f * x; }
__device__ __forceinline__ int rl_i(int v, int l) { return __builtin_amdgcn_readlane(v, l); }
__device__ __forceinline__ unsigned int q8b(float x, float inv) {  // biased uint8
  float q = fminf(fmaxf(x * inv, -127.f), 127.f);
  return (unsigned int)((int)rintf(q) + 128) & 255u;
}
#define NEG_INF __int_as_float(0xff800000)

// ============================ bucket-sorted CSR build ============================
__global__ __launch_bounds__(256) void bucket_hist(const int* __restrict__ dst,
                                                   int* __restrict__ bhist, int E, int NB) {
  __shared__ int lh[512];
  int t = threadIdx.x;
  lh[t] = 0; lh[t + 256] = 0;
  __syncthreads();
  int e0 = blockIdx.x * EPB;
  #pragma unroll
  for (int i = 0; i < EPB / 256; i++) {
    int e = e0 + i * 256 + t;
    if (e < E) atomicAdd(&lh[dst[e] >> 8], 1);
  }
  __syncthreads();
  for (int x = t; x < NB; x += 256) {
    int c = lh[x];
    if (c > 0) atomicAdd(&bhist[x], c);
  }
}

__global__ __launch_bounds__(512) void scan_buckets(const int* __restrict__ bhist,
                                                    int* __restrict__ boffs, int n) {
  __shared__ int sh[512];
  int t = threadIdx.x;
  int v = (t < n) ? bhist[t] : 0;
  sh[t] = v; __syncthreads();
  for (int d = 1; d < 512; d <<= 1) {
    int w = (t >= d) ? sh[t - d] : 0;
    __syncthreads();
    sh[t] += w;
    __syncthreads();
  }
  if (t <= n) boffs[t] = sh[t] - v;
}

__global__ __launch_bounds__(256) void bucket_scatter(const int* __restrict__ src,
                                                      const int* __restrict__ dst,
                                                      const int* __restrict__ boffs,
                                                      int* __restrict__ gcur,
                                                      unsigned int* __restrict__ sorted,
                                                      int E, int NB) {
  __shared__ int lh[512];
  int t = threadIdx.x;
  lh[t] = 0; lh[t + 256] = 0;
  __syncthreads();
  int e0 = blockIdx.x * EPB;
  #pragma unroll
  for (int i = 0; i < EPB / 256; i++) {
    int e = e0 + i * 256 + t;
    if (e < E) atomicAdd(&lh[dst[e] >> 8], 1);
  }
  __syncthreads();
  for (int x = t; x < NB; x += 256) {
    int c = lh[x];
    lh[x] = (c > 0) ? (boffs[x] + atomicAdd(&gcur[x], c)) : 0;
  }
  __syncthreads();
  #pragma unroll
  for (int i = 0; i < EPB / 256; i++) {
    int e = e0 + i * 256 + t;
    if (e < E) {
      int d = dst[e];
      int pos = atomicAdd(&lh[d >> 8], 1);
      sorted[pos] = ((unsigned int)src[e] << 8) | (unsigned int)(d & 255);
    }
  }
}

__global__ __launch_bounds__(256) void bucket_count(const unsigned int* __restrict__ sorted,
                                                    const int* __restrict__ boffs,
                                                    int* __restrict__ counts, int N) {
  __shared__ int cnt[256];
  int b = blockIdx.x, t = threadIdx.x;
  cnt[t] = 0; __syncthreads();
  int beg = boffs[b], end = boffs[b + 1];
  for (int p = beg + t; p < end; p += 256)
    atomicAdd(&cnt[sorted[p] & 255u], 1);
  __syncthreads();
  int d = b * 256 + t;
  if (d < N) counts[d] = cnt[t];
}

__global__ __launch_bounds__(256) void scan_block(const int* __restrict__ cnt,
                                                  int* __restrict__ offs,
                                                  int* __restrict__ bsum, int n) {
  __shared__ int sh[256];
  int t = threadIdx.x;
  int i = blockIdx.x * 256 + t;
  int v = (i < n) ? cnt[i] : 0;
  sh[t] = v; __syncthreads();
  for (int d = 1; d < 256; d <<= 1) {
    int w = (t >= d) ? sh[t - d] : 0;
    __syncthreads();
    sh[t] += w;
    __syncthreads();
  }
  if (i < n) offs[i] = sh[t] - v;
  if (t == 255) bsum[blockIdx.x] = sh[255];
}

__global__ __launch_bounds__(512) void scan_top(int* __restrict__ bsum, int nb) {
  __shared__ int sh[512];
  int t = threadIdx.x;
  int v = (t < nb) ? bsum[t] : 0;
  sh[t] = v; __syncthreads();
  for (int d = 1; d < 512; d <<= 1) {
    int w = (t >= d) ? sh[t - d] : 0;
    __syncthreads();
    sh[t] += w;
    __syncthreads();
  }
  if (t < nb) bsum[t] = sh[t] - v;
}

__global__ __launch_bounds__(256) void scan_add(int* __restrict__ offs,
                                                const int* __restrict__ bsum, int n, int E) {
  int i = blockIdx.x * 256 + threadIdx.x;
  if (i < n) offs[i] += bsum[i >> 8];
  if (i == n) offs[n] = E;
}

__global__ __launch_bounds__(256) void bucket_place(const unsigned int* __restrict__ sorted,
                                                    const int* __restrict__ boffs,
                                                    const int* __restrict__ offs,
                                                    int* __restrict__ ssrc, int N) {
  __shared__ int offl[256];
  __shared__ int cur[256];
  int b = blockIdx.x, t = threadIdx.x;
  int d = b * 256 + t;
  offl[t] = (d < N) ? offs[d] : 0;
  cur[t] = 0;
  __syncthreads();
  int beg = boffs[b], end = boffs[b + 1];
  for (int p = beg + t; p < end; p += 256) {
    unsigned int pk = sorted[p];
    int dl = pk & 255u;
    int r = atomicAdd(&cur[dl], 1);
    ssrc[offl[dl] + r] = (int)(pk >> 8);
  }
}

// ============================ GEMM (K=128) -> biased uint8 rows + scale ============
template <int COLS, bool ABF16>
__global__ __launch_bounds__(256) void gemm_k128(const void* __restrict__ Av,
                                                 const void* __restrict__ Wv,
                                                 unsigned int* __restrict__ Cq,
                                                 float* __restrict__ scl,
                                                 int nrows) {
  constexpr int TN = COLS / 16;
  __shared__ float xs[16][132];
  __shared__ float wsd[16][COLS];
  const int t = threadIdx.x;
  const int ty = t >> 4, tx = t & 15;
  const int row0 = blockIdx.x * 128;
  float acc[8][TN] = {};

  const int r = t >> 1, hf = t & 1;
  const int grow = row0 + r;

  for (int k0 = 0; k0 < 128; k0 += 16) {
    float av[8];
    if (grow < nrows) {
      if constexpr (ABF16) {
        const unsigned short* ap = (const unsigned short*)Av + (size_t)grow * 128 + k0 + hf * 8;
        uint4 u = *(const uint4*)ap;
        av[0] = bf2f(u.x & 0xffffu); av[1] = bf2f(u.x >> 16);
        av[2] = bf2f(u.y & 0xffffu); av[3] = bf2f(u.y >> 16);
        av[4] = bf2f(u.z & 0xffffu); av[5] = bf2f(u.z >> 16);
        av[6] = bf2f(u.w & 0xffffu); av[7] = bf2f(u.w >> 16);
      } else {
        const float* ap = (const float*)Av + (size_t)grow * 128 + k0 + hf * 8;
        float4 f0 = *(const float4*)ap;
        float4 f1 = *(const float4*)(ap + 4);
        av[0] = f0.x; av[1] = f0.y; av[2] = f0.z; av[3] = f0.w;
        av[4] = f1.x; av[5] = f1.y; av[6] = f1.z; av[7] = f1.w;
      }
    } else {
      #pragma unroll
      for (int j = 0; j < 8; j++) av[j] = 0.f;
    }
    #pragma unroll
    for (int j = 0; j < 8; j++) xs[hf * 8 + j][r] = av[j];

    if constexpr (COLS == 128) {
      const float* wp = (const float*)Wv + (size_t)(k0 + ty) * 128 + tx * 8;
      float4 f0 = *(const float4*)wp;
      float4 f1 = *(const float4*)(wp + 4);
      wsd[ty][tx * 8 + 0] = f0.x; wsd[ty][tx * 8 + 1] = f0.y;
      wsd[ty][tx * 8 + 2] = f0.z; wsd[ty][tx * 8 + 3] = f0.w;
      wsd[ty][tx * 8 + 4] = f1.x; wsd[ty][tx * 8 + 5] = f1.y;
      wsd[ty][tx * 8 + 6] = f1.z; wsd[ty][tx * 8 + 7] = f1.w;
    } else {
      const int kk = t >> 4, c = (t & 15) * 4;
      const float* wp = (const float*)Wv + (size_t)(k0 + kk) * 64 + c;
      float4 f0 = *(const float4*)wp;
      wsd[kk][c + 0] = f0.x; wsd[kk][c + 1] = f0.y; wsd[kk][c + 2] = f0.z; wsd[kk][c + 3] = f0.w;
    }
    __syncthreads();

    #pragma unroll
    for (int kk = 0; kk < 16; kk++) {
      float a[8];
      #pragma unroll
      for (int i = 0; i < 8; i++) a[i] = xs[kk][ty * 8 + i];
      float b[TN];
      if constexpr (COLS == 128) {
        #pragma unroll
        for (int j = 0; j < 4; j++) { b[j] = wsd[kk][tx * 4 + j]; b[4 + j] = wsd[kk][64 + tx * 4 + j]; }
      } else {
        #pragma unroll
        for (int j = 0; j < TN; j++) b[j] = wsd[kk][tx * 4 + j];
      }
      #pragma unroll
      for (int i = 0; i < 8; i++)
        #pragma unroll
        for (int j = 0; j < TN; j++) acc[i][j] += a[i] * b[j];
    }
    __syncthreads();
  }

  // ---- epilogue: per-row absmax (shfl over the 16 tx lanes), quantize biased u8 ----
  #pragma unroll
  for (int i = 0; i < 8; i++) {
    float mx = 0.f;
    #pragma unroll
    for (int j = 0; j < TN; j++) mx = fmaxf(mx, fabsf(acc[i][j]));
    mx = fmaxf(mx, __shfl_xor(mx, 1));
    mx = fmaxf(mx, __shfl_xor(mx, 2));
    mx = fmaxf(mx, __shfl_xor(mx, 4));
    mx = fmaxf(mx, __shfl_xor(mx, 8));
    float inv = mx > 0.f ? 127.f / mx : 0.f;
    int rr = row0 + ty * 8 + i;
    if (rr < nrows) {
      if constexpr (COLS == 128) {
        unsigned int lo = q8b(acc[i][0], inv) | (q8b(acc[i][1], inv) << 8) |
                          (q8b(acc[i][2], inv) << 16) | (q8b(acc[i][3], inv) << 24);
        unsigned int hi = q8b(acc[i][4], inv) | (q8b(acc[i][5], inv) << 8) |
                          (q8b(acc[i][6], inv) << 16) | (q8b(acc[i][7], inv) << 24);
        Cq[(size_t)rr * 32 + tx] = lo;        // ch tx*4..+3
        Cq[(size_t)rr * 32 + 16 + tx] = hi;   // ch 64+tx*4..+3
      } else {
        unsigned int lo = q8b(acc[i][0], inv) | (q8b(acc[i][1], inv) << 8) |
                          (q8b(acc[i][2], inv) << 16) | (q8b(acc[i][3], inv) << 24);
        Cq[(size_t)rr * 16 + tx] = lo;        // ch tx*4..+3
      }
      if (tx == 0) scl[rr] = mx * (1.f / 127.f);
    }
  }
}

// ============================ attention logits (biased u8 in) ============================
template <int H>
__global__ __launch_bounds__(256) void attn_logits(const void* __restrict__ hq,
                                                   const float* __restrict__ scl,
                                                   const float* __restrict__ att_s,
                                                   const float* __restrict__ att_d,
                                                   float* __restrict__ asrc,
                                                   float* __restrict__ adst, int n) {
  int node = (int)((blockIdx.x * (unsigned)blockDim.x + threadIdx.x) >> 6);
  int lane = threadIdx.x & 63;
  if (node >= n) return;
  float sv = scl[node];
  float ss, sd;
  if constexpr (H == 2) {
    unsigned int v = ((const unsigned short*)hq)[(size_t)node * 64 + lane];  // ch 2l,2l+1
    float hv0 = (float)(v & 255u) - 128.f;
    float hv1 = (float)((v >> 8) & 255u) - 128.f;
    int ch = lane * 2;
    ss = hv0 * att_s[ch] + hv1 * att_s[ch + 1];
    sd = hv0 * att_d[ch] + hv1 * att_d[ch + 1];
  } else {
    float hv = (float)((const unsigned char*)hq)[(size_t)node * 64 + lane] - 128.f;
    ss = hv * att_s[lane];
    sd = hv * att_d[lane];
  }
  #pragma unroll
  for (int d = (H == 1 ? 32 : 16); d >= 1; d >>= 1) {
    ss += __shfl_xor(ss, d);
    sd += __shfl_xor(sd, d);
  }
  int gl = (H == 2) ? (lane & 31) : lane;
  int hd = (H == 2) ? (lane >> 5) : 0;
  if (gl == 0) {
    asrc[(size_t)node * H + hd] = ss * sv;
    adst[(size_t)node * H + hd] = sd * sv;
  }
}

// ====== softmax-aggregate: flash-style, biased-u8 rows, LDS p-broadcast, 8-deep MLP ====
// Per-edge VALU (H=2): readlane(s) + 2 cvt_ubyte + 2 fma; p comes from a per-wave
// LDS slab via immediate-offset ds_read (LGKM pipe). Bias (+128) removed at the end
// via SPF = running sum of folded weights.
template <int H, bool ELU_OUT, bool F32OUT>
__global__ __launch_bounds__(256) void agg_gather(const void* __restrict__ hq,
                                                  const float* __restrict__ scl,
                                                  const float* __restrict__ asrc,
                                                  const float* __restrict__ adst,
                                                  const int* __restrict__ offs,
                                                  const int* __restrict__ ssrc,
                                                  const float* __restrict__ bias,
                                                  void* __restrict__ outv, int n) {
  __shared__ float pshare[4][64];
  __shared__ int vshare[4][64];  // H==1 only: row byte offsets
  const int tid = threadIdx.x;
  const int wid = tid >> 6;
  int node = (int)((blockIdx.x * (unsigned)blockDim.x + tid) >> 6);
  int lane = tid & 63;
  if (node >= n) return;  // node uniform per wave -> whole wave exits
  const int hd = lane >> 5;
  const int beg = offs[node], end = offs[node + 1];
  const unsigned short* hq16 = (const unsigned short*)hq;
  const unsigned char* hqb = (const unsigned char*)hq;

  float adh, m, acc0, acc1, d;
  float SPF = 0.f;  // running sum of folded p (for the -128 bias correction)
  const float s_self = scl[node];
  if constexpr (H == 2) {
    float2 adv = ((const float2*)adst)[node];
    float2 asv = ((const float2*)asrc)[node];
    adh = hd ? adv.y : adv.x;
    m = lrelu02((hd ? asv.y : asv.x) + adh);  // e_self per head
    unsigned int v = hq16[((size_t)node << 6) + lane];  // ch 2l,2l+1
    acc0 = s_self * ((float)(v & 255u) - 128.f);  // p_self = 1, exact decode
    acc1 = s_self * ((float)((v >> 8) & 255u) - 128.f);
  } else {
    adh = adst[node];
    m = lrelu02(asrc[node] + adh);
    if (hd == 0) {
      unsigned int v = hq16[((size_t)node << 5) + lane];
      acc0 = s_self * ((float)(v & 255u) - 128.f);
      acc1 = s_self * ((float)((v >> 8) & 255u) - 128.f);
    } else {
      acc0 = 0.f; acc1 = 0.f;
    }
  }
  d = 1.f;  // p_self

  constexpr int CH = (H == 2) ? 32 : 64;
  const int lvoff = (lane & 31) * 2;  // H==1 byte offset within row
  for (int pos = beg; pos < end; pos += CH) {
    const int len = min(CH, end - pos);
    int li = (H == 2) ? (lane & 31) : lane;
    bool valid = li < len;
    int s_l = valid ? ssrc[pos + li] : 0;      // pad: node 0 (safe), p will be 0
    float scl_l = valid ? scl[s_l] : 0.f;
    float e_l;
    if constexpr (H == 2) {
      float a = asrc[(s_l << 1) + hd];
      e_l = valid ? lrelu02(a + adh) : NEG_INF;
    } else {
      float a = asrc[s_l];
      e_l = valid ? lrelu02(a + adh) : NEG_INF;
    }
    float mc = e_l;
    #pragma unroll
    for (int dlt = CH >> 1; dlt >= 1; dlt >>= 1) mc = fmaxf(mc, __shfl_xor(mc, dlt));
    float m_new = fmaxf(m, mc);
    float f = __expf(m - m_new);
    float p_l = __expf(e_l - m_new);  // 0 for invalid lanes
    float sc = p_l;
    #pragma unroll
    for (int dlt = CH >> 1; dlt >= 1; dlt >>= 1) sc += __shfl_xor(sc, dlt);
    d = d * f + sc;
    acc0 *= f; acc1 *= f;
    m = m_new;
    p_l *= scl_l;  // fold per-row dequant scale (post-denominator)

    // stage folded p (and H==1 row offsets) for the inner loop; SPF chunk reduce
    pshare[wid][lane] = p_l;
    float spf = p_l;
    if constexpr (H == 2) {
      #pragma unroll
      for (int dlt = 16; dlt >= 1; dlt >>= 1) spf += __shfl_xor(spf, dlt);  // per head
    } else {
      vshare[wid][lane] = s_l << 6;  // row byte offset (64 B rows)
      #pragma unroll
      for (int dlt = 32; dlt >= 1; dlt >>= 1) spf += __shfl_xor(spf, dlt);  // all edges
    }
    SPF = SPF * f + spf;

    if constexpr (H == 2) {
      const int ng = (len + 7) >> 3;
      for (int g = 0; g < ng; g++) {
        const int jb = g * 8;  // wave-uniform
        unsigned short v[8];
        #pragma unroll
        for (int k = 0; k < 8; k++) {
          int s = rl_i(s_l, jb + k);  // SGPR row id -> SALU addressing
          v[k] = hq16[((size_t)(unsigned)s << 6) + lane];
        }
        float pv[8];
        #pragma unroll
        for (int k = 0; k < 8; k++) pv[k] = pshare[wid][hd * 32 + jb + k];
        #pragma unroll
        for (int k = 0; k < 8; k++) {
          unsigned int w = v[k];
          acc0 = fmaf(pv[k], (float)(w & 255u), acc0);
          acc1 = fmaf(pv[k], (float)((w >> 8) & 255u), acc1);
        }
      }
    } else {
      const int npair = (len + 1) >> 1;
      const int ng = (npair + 7) >> 3;
      for (int g = 0; g < ng; g++) {
        const int jb = g * 16;  // edge base, wave-uniform
        unsigned short v[8];
        #pragma unroll
        for (int k = 0; k < 8; k++) {
          int voff = vshare[wid][jb + 2 * k + hd];   // ds_read, imm offset + hd base
          v[k] = *(const unsigned short*)(hqb + (unsigned)voff + lvoff);
        }
        float pv[8];
        #pragma unroll
        for (int k = 0; k < 8; k++) pv[k] = pshare[wid][jb + 2 * k + hd];
        #pragma unroll
        for (int k = 0; k < 8; k++) {
          unsigned int w = v[k];
          acc0 = fmaf(pv[k], (float)(w & 255u), acc0);
          acc1 = fmaf(pv[k], (float)((w >> 8) & 255u), acc1);
        }
      }
    }
  }

  if constexpr (H == 1) {  // halves accumulated different edges
    acc0 += __shfl_xor(acc0, 32);
    acc1 += __shfl_xor(acc1, 32);
  }
  // remove the +128 bias: edge contributions become p*(u-128)
  acc0 = fmaf(-128.f, SPF, acc0);
  acc1 = fmaf(-128.f, SPF, acc1);

  const float inv = 1.f / d;
  if constexpr (H == 2) {
    float2 bv = ((const float2*)bias)[lane];
    float v0 = acc0 * inv + bv.x;
    float v1 = acc1 * inv + bv.y;
    if (ELU_OUT) {
      v0 = v0 > 0.f ? v0 : (__expf(v0) - 1.f);
      v1 = v1 > 0.f ? v1 : (__expf(v1) - 1.f);
    }
    if constexpr (F32OUT) {
      ((float2*)outv)[(size_t)node * 64 + lane] = make_float2(v0, v1);
    } else {
      unsigned int pk = (unsigned int)f2bf(v0) | ((unsigned int)f2bf(v1) << 16);
      ((unsigned int*)outv)[(size_t)node * 64 + lane] = pk;
    }
  } else {
    if (hd == 0) {
      float2 bv = ((const float2*)bias)[lane];
      float v0 = acc0 * inv + bv.x;
      float v1 = acc1 * inv + bv.y;
      if (ELU_OUT) {
        v0 = v0 > 0.f ? v0 : (__expf(v0) - 1.f);
        v1 = v1 > 0.f ? v1 : (__expf(v1) - 1.f);
      }
      if constexpr (F32OUT) {
        ((float2*)outv)[(size_t)node * 32 + lane] = make_float2(v0, v1);
      } else {
        unsigned int pk = (unsigned int)f2bf(v0) | ((unsigned int)f2bf(v1) << 16);
        ((unsigned int*)outv)[(size_t)node * 32 + lane] = pk;
      }
    }
  }
}

// ============================ launch ============================
extern "C" void kernel_launch(void* const* d_in, const int* in_sizes, int n_in,
                              void* d_out, int out_size, void* d_ws, size_t ws_size,
                              hipStream_t stream) {
  const int N = in_sizes[0] / FIN;      // 100000
  const int E = in_sizes[1] / 2;        // 1600000

  const void*  x   = d_in[0];
  const int*   ei  = (const int*)d_in[1];
  const void*  W1  = d_in[2];
  const float* as1 = (const float*)d_in[3];
  const float* ad1 = (const float*)d_in[4];
  const float* b1  = (const float*)d_in[5];
  const void*  W2  = d_in[6];
  const float* as2 = (const float*)d_in[7];
  const float* ad2 = (const float*)d_in[8];
  const float* b2  = (const float*)d_in[9];

  const int* e_src = ei;
  const int* e_dst = ei + E;

  char* p = (char*)d_ws;
  auto carve = [&](size_t bytes) {
    char* q = p;
    p += (bytes + 255) & ~(size_t)255;
    return (void*)q;
  };
  unsigned int* h1q  = (unsigned int*)carve((size_t)N * 128);      // u8 rows, layer1
  float* scl1        = (float*)carve((size_t)N * 4);
  unsigned int* h2q  = (unsigned int*)carve((size_t)N * 64);       // u8 rows, layer2
  float* scl2        = (float*)carve((size_t)N * 4);
  unsigned short* buf2 = (unsigned short*)carve((size_t)N * HC1 * 2);  // bf16 layer1 out
  float* asrc1 = (float*)carve((size_t)N * 2 * 4);
  float* adst1 = (float*)carve((size_t)N * 2 * 4);
  float* asrc2 = (float*)carve((size_t)N * 4);
  float* adst2 = (float*)carve((size_t)N * 4);
  int* counts  = (int*)carve((size_t)N * 4);
  int* offs    = (int*)carve((size_t)(N + 1) * 4);
  int* bsum    = (int*)carve(512 * 4);
  int* bhist   = (int*)carve((size_t)2 * 512 * 4);  // bhist + gcur, one memset
  int* gcur    = bhist + 512;
  int* boffs   = (int*)carve(513 * 4);
  unsigned int* sorted = (unsigned int*)carve((size_t)E * 4);
  int* ssrc    = (int*)carve((size_t)E * 4);

  const int NB = (N + 255) >> 8;
  const int nb = (N + 255) / 256;
  const int sgrid = (E + EPB - 1) / EPB;
  const int wgrid = (int)(((size_t)N * 64 + 255) / 256);
  const int ggrid = (N + 127) / 128;

  // ---- CSR build (bucket-sorted, shared by both layers) ----
  hipMemsetAsync(bhist, 0, (size_t)2 * 512 * 4, stream);
  bucket_hist<<<sgrid, 256, 0, stream>>>(e_dst, bhist, E, NB);
  scan_buckets<<<1, 512, 0, stream>>>(bhist, boffs, NB);
  bucket_scatter<<<sgrid, 256, 0, stream>>>(e_src, e_dst, boffs, gcur, sorted, E, NB);
  bucket_count<<<NB, 256, 0, stream>>>(sorted, boffs, counts, N);
  scan_block<<<nb, 256, 0, stream>>>(counts, offs, bsum, N);
  scan_top<<<1, 512, 0, stream>>>(bsum, nb);
  scan_add<<<(N + 256) / 256, 256, 0, stream>>>(offs, bsum, N, E);
  bucket_place<<<NB, 256, 0, stream>>>(sorted, boffs, offs, ssrc, N);

  // ---- layer 1 ----
  gemm_k128<128, false><<<ggrid, 256, 0, stream>>>(x, W1, h1q, scl1, N);
  attn_logits<2><<<wgrid, 256, 0, stream>>>(h1q, scl1, as1, ad1, asrc1, adst1, N);
  agg_gather<2, true, false><<<wgrid, 256, 0, stream>>>(h1q, scl1, asrc1, adst1, offs, ssrc,
                                                        b1, buf2, N);

  // ---- layer 2 ----
  gemm_k128<64, true><<<ggrid, 256, 0, stream>>>(buf2, W2, h2q, scl2, N);
  attn_logits<1><<<wgrid, 256, 0, stream>>>(h2q, scl2, as2, ad2, asrc2, adst2, N);
  agg_gather<1, false, true><<<wgrid, 256, 0, stream>>>(h2q, scl2, asrc2, adst2, offs, ssrc,
                                                        b2, d_out, N);
}

// Round 9
// 346.032 us; speedup vs baseline: 1.3805x; 1.1670x over previous
//
#include <hip/hip_runtime.h>
#include <hip/hip_bf16.h>
#include <cstdint>
#include <cstddef>

// Inputs/outputs fp32 (reference dtype). Node features stored as BIASED uint8
// (q+128) with per-row scale. Round-8 evidence: gemm_k128 fp32-VALU GEMM is the
// top kernel (76us, 8192 VALU-FMA/wave). This round: bf16 MFMA GEMM (64 MFMA/wave).
static constexpr int FIN = 128;
static constexpr int HC1 = 128;  // layer1: H=2, C=64, concat
static constexpr int EPB = 4096; // edges per block in bucket_scatter

typedef __attribute__((ext_vector_type(8))) short short8;   // 8 bf16 = 4 VGPRs
typedef __attribute__((ext_vector_type(4))) float f32x4;    // MFMA acc

__device__ __forceinline__ float bf2f(unsigned int u) { return __uint_as_float(u << 16); }
__device__ __forceinline__ unsigned short f2bf(float f) {  // round-to-nearest-even
  unsigned int u = __float_as_uint(f);
  return (unsigned short)((u + 0x7fff + ((u >> 16) & 1)) >> 16);
}
__device__ __forceinline__ float lrelu02(float x) { return x > 0.f ? x : 0.2f * x; }
__device__ __forceinline__ int rl_i(int v, int l) { return __builtin_amdgcn_readlane(v, l); }
__device__ __forceinline__ unsigned int q8b(float x, float inv) {  // biased uint8
  float q = fminf(fmaxf(x * inv, -127.f), 127.f);
  return (unsigned int)((int)rintf(q) + 128) & 255u;
}
#define NEG_INF __int_as_float(0xff800000)

// ============================ bucket-sorted CSR build ============================
__global__ __launch_bounds__(256) void bucket_hist(const int* __restrict__ dst,
                                                   int* __restrict__ bhist, int E, int NB) {
  __shared__ int lh[512];
  int t = threadIdx.x;
  lh[t] = 0; lh[t + 256] = 0;
  __syncthreads();
  int e0 = blockIdx.x * EPB;
  #pragma unroll
  for (int i = 0; i < EPB / 256; i++) {
    int e = e0 + i * 256 + t;
    if (e < E) atomicAdd(&lh[dst[e] >> 8], 1);
  }
  __syncthreads();
  for (int x = t; x < NB; x += 256) {
    int c = lh[x];
    if (c > 0) atomicAdd(&bhist[x], c);
  }
}

__global__ __launch_bounds__(512) void scan_buckets(const int* __restrict__ bhist,
                                                    int* __restrict__ boffs, int n) {
  __shared__ int sh[512];
  int t = threadIdx.x;
  int v = (t < n) ? bhist[t] : 0;
  sh[t] = v; __syncthreads();
  for (int d = 1; d < 512; d <<= 1) {
    int w = (t >= d) ? sh[t - d] : 0;
    __syncthreads();
    sh[t] += w;
    __syncthreads();
  }
  if (t <= n) boffs[t] = sh[t] - v;
}

__global__ __launch_bounds__(256) void bucket_scatter(const int* __restrict__ src,
                                                      const int* __restrict__ dst,
                                                      const int* __restrict__ boffs,
                                                      int* __restrict__ gcur,
                                                      unsigned int* __restrict__ sorted,
                                                      int E, int NB) {
  __shared__ int lh[512];
  int t = threadIdx.x;
  lh[t] = 0; lh[t + 256] = 0;
  __syncthreads();
  int e0 = blockIdx.x * EPB;
  #pragma unroll
  for (int i = 0; i < EPB / 256; i++) {
    int e = e0 + i * 256 + t;
    if (e < E) atomicAdd(&lh[dst[e] >> 8], 1);
  }
  __syncthreads();
  for (int x = t; x < NB; x += 256) {
    int c = lh[x];
    lh[x] = (c > 0) ? (boffs[x] + atomicAdd(&gcur[x], c)) : 0;
  }
  __syncthreads();
  #pragma unroll
  for (int i = 0; i < EPB / 256; i++) {
    int e = e0 + i * 256 + t;
    if (e < E) {
      int d = dst[e];
      int pos = atomicAdd(&lh[d >> 8], 1);
      sorted[pos] = ((unsigned int)src[e] << 8) | (unsigned int)(d & 255);
    }
  }
}

__global__ __launch_bounds__(256) void bucket_count(const unsigned int* __restrict__ sorted,
                                                    const int* __restrict__ boffs,
                                                    int* __restrict__ counts, int N) {
  __shared__ int cnt[256];
  int b = blockIdx.x, t = threadIdx.x;
  cnt[t] = 0; __syncthreads();
  int beg = boffs[b], end = boffs[b + 1];
  for (int p = beg + t; p < end; p += 256)
    atomicAdd(&cnt[sorted[p] & 255u], 1);
  __syncthreads();
  int d = b * 256 + t;
  if (d < N) counts[d] = cnt[t];
}

__global__ __launch_bounds__(256) void scan_block(const int* __restrict__ cnt,
                                                  int* __restrict__ offs,
                                                  int* __restrict__ bsum, int n) {
  __shared__ int sh[256];
  int t = threadIdx.x;
  int i = blockIdx.x * 256 + t;
  int v = (i < n) ? cnt[i] : 0;
  sh[t] = v; __syncthreads();
  for (int d = 1; d < 256; d <<= 1) {
    int w = (t >= d) ? sh[t - d] : 0;
    __syncthreads();
    sh[t] += w;
    __syncthreads();
  }
  if (i < n) offs[i] = sh[t] - v;
  if (t == 255) bsum[blockIdx.x] = sh[255];
}

__global__ __launch_bounds__(512) void scan_top(int* __restrict__ bsum, int nb) {
  __shared__ int sh[512];
  int t = threadIdx.x;
  int v = (t < nb) ? bsum[t] : 0;
  sh[t] = v; __syncthreads();
  for (int d = 1; d < 512; d <<= 1) {
    int w = (t >= d) ? sh[t - d] : 0;
    __syncthreads();
    sh[t] += w;
    __syncthreads();
  }
  if (t < nb) bsum[t] = sh[t] - v;
}

__global__ __launch_bounds__(256) void scan_add(int* __restrict__ offs,
                                                const int* __restrict__ bsum, int n, int E) {
  int i = blockIdx.x * 256 + threadIdx.x;
  if (i < n) offs[i] += bsum[i >> 8];
  if (i == n) offs[n] = E;
}

__global__ __launch_bounds__(256) void bucket_place(const unsigned int* __restrict__ sorted,
                                                    const int* __restrict__ boffs,
                                                    const int* __restrict__ offs,
                                                    int* __restrict__ ssrc, int N) {
  __shared__ int offl[256];
  __shared__ int cur[256];
  int b = blockIdx.x, t = threadIdx.x;
  int d = b * 256 + t;
  offl[t] = (d < N) ? offs[d] : 0;
  cur[t] = 0;
  __syncthreads();
  int beg = boffs[b], end = boffs[b + 1];
  for (int p = beg + t; p < end; p += 256) {
    unsigned int pk = sorted[p];
    int dl = pk & 255u;
    int r = atomicAdd(&cur[dl], 1);
    ssrc[offl[dl] + r] = (int)(pk >> 8);
  }
}

// ================= MFMA GEMM (K=128) -> biased uint8 rows + per-row scale =========
// Block = 4 waves x 128 rows; W^T staged bf16 in LDS (+8 pad -> conflict-light
// b128 B-frag reads). Wave w owns rows [blk*128+w*32, +32) = 2 row-tiles of 16.
// mfma_f32_16x16x32_bf16: A[m=lane&15][k=quad*8+j]; B[n=lane&15][k=quad*8+j];
// C col=lane&15, row=quad*4+reg  [verified layouts, guide §3].
template <int COLS, bool AF32>
__global__ __launch_bounds__(256) void gemm_mfma(const void* __restrict__ Av,
                                                 const float* __restrict__ Wv,
                                                 unsigned char* __restrict__ Cq,
                                                 float* __restrict__ scl,
                                                 int nrows) {
  constexpr int NT = COLS / 16;       // col-tiles: 8 or 4
  __shared__ unsigned short WT[COLS][136];            // [col][k], +8 bf16 pad
  __shared__ __align__(16) unsigned char pack[4][16 * COLS];

  const int tid = threadIdx.x;
  // ---- stage W^T (fp32 -> bf16), coalesced reads, one-time ----
  constexpr int NPC = COLS / 4;
  for (int idx = tid; idx < 128 * NPC; idx += 256) {
    int k = idx / NPC;
    int n0 = (idx - k * NPC) * 4;
    float4 wv = *(const float4*)(Wv + (size_t)k * COLS + n0);
    WT[n0 + 0][k] = f2bf(wv.x);
    WT[n0 + 1][k] = f2bf(wv.y);
    WT[n0 + 2][k] = f2bf(wv.z);
    WT[n0 + 3][k] = f2bf(wv.w);
  }
  __syncthreads();

  const int w = tid >> 6, lane = tid & 63;
  const int quad = lane >> 4, cl = lane & 15;
  const int rbase = blockIdx.x * 128 + w * 32;

  f32x4 acc[2][NT];
  #pragma unroll
  for (int rt = 0; rt < 2; rt++)
    #pragma unroll
    for (int ct = 0; ct < NT; ct++) acc[rt][ct] = (f32x4){0.f, 0.f, 0.f, 0.f};

  #pragma unroll
  for (int kc = 0; kc < 4; kc++) {
    const int k0 = kc * 32 + quad * 8;
    short8 a[2];
    #pragma unroll
    for (int rt = 0; rt < 2; rt++) {
      int row = rbase + rt * 16 + cl;
      row = min(row, nrows - 1);  // clamp; out-of-range rows discarded at store
      if constexpr (AF32) {
        const float* ap = (const float*)Av + (size_t)row * 128 + k0;
        float4 f0 = *(const float4*)ap;
        float4 f1 = *(const float4*)(ap + 4);
        short8 t;
        t[0] = (short)f2bf(f0.x); t[1] = (short)f2bf(f0.y);
        t[2] = (short)f2bf(f0.z); t[3] = (short)f2bf(f0.w);
        t[4] = (short)f2bf(f1.x); t[5] = (short)f2bf(f1.y);
        t[6] = (short)f2bf(f1.z); t[7] = (short)f2bf(f1.w);
        a[rt] = t;
      } else {
        a[rt] = *(const short8*)((const unsigned short*)Av + (size_t)row * 128 + k0);
      }
    }
    #pragma unroll
    for (int ct = 0; ct < NT; ct++) {
      short8 b = *(const short8*)&WT[ct * 16 + cl][k0];
      #pragma unroll
      for (int rt = 0; rt < 2; rt++)
        acc[rt][ct] = __builtin_amdgcn_mfma_f32_16x16x32_bf16(a[rt], b, acc[rt][ct], 0, 0, 0);
    }
  }

  // ---- epilogue: per-row absmax -> biased u8, LDS repack, coalesced stores ----
  #pragma unroll
  for (int rt = 0; rt < 2; rt++) {
    #pragma unroll
    for (int r = 0; r < 4; r++) {
      float mx = 0.f;
      #pragma unroll
      for (int ct = 0; ct < NT; ct++) mx = fmaxf(mx, fabsf(acc[rt][ct][r]));
      mx = fmaxf(mx, __shfl_xor(mx, 1));   // reduce over 16 cols (intra-quad)
      mx = fmaxf(mx, __shfl_xor(mx, 2));
      mx = fmaxf(mx, __shfl_xor(mx, 4));
      mx = fmaxf(mx, __shfl_xor(mx, 8));
      float inv = mx > 0.f ? 127.f / mx : 0.f;
      int grow = rbase + rt * 16 + quad * 4 + r;
      if (cl == 0 && grow < nrows) scl[grow] = mx * (1.f / 127.f);
      #pragma unroll
      for (int ct = 0; ct < NT; ct++)
        pack[w][(quad * 4 + r) * COLS + ct * 16 + cl] =
            (unsigned char)q8b(acc[rt][ct][r], inv);
    }
    __syncthreads();  // order LDS writes (cross-lane) before reads; uniform barrier
    // copy 16 rows x COLS bytes, fully coalesced 16B stores
    if constexpr (COLS == 128) {
      #pragma unroll
      for (int i = 0; i < 2; i++) {
        int off = i * 1024 + lane * 16;
        uint4 v = *(const uint4*)&pack[w][off];
        int grow = rbase + rt * 16 + (off >> 7);
        if (grow < nrows)
          *(uint4*)(Cq + (size_t)grow * 128 + (off & 127)) = v;
      }
    } else {
      int off = lane * 16;
      uint4 v = *(const uint4*)&pack[w][off];
      int grow = rbase + rt * 16 + (off >> 6);
      if (grow < nrows)
        *(uint4*)(Cq + (size_t)grow * 64 + (off & 63)) = v;
    }
    __syncthreads();  // protect pack slab before rt=1 overwrites
  }
}

// ============================ attention logits (biased u8 in) ============================
template <int H>
__global__ __launch_bounds__(256) void attn_logits(const void* __restrict__ hq,
                                                   const float* __restrict__ scl,
                                                   const float* __restrict__ att_s,
                                                   const float* __restrict__ att_d,
                                                   float* __restrict__ asrc,
                                                   float* __restrict__ adst, int n) {
  int node = (int)((blockIdx.x * (unsigned)blockDim.x + threadIdx.x) >> 6);
  int lane = threadIdx.x & 63;
  if (node >= n) return;
  float sv = scl[node];
  float ss, sd;
  if constexpr (H == 2) {
    unsigned int v = ((const unsigned short*)hq)[(size_t)node * 64 + lane];  // ch 2l,2l+1
    float hv0 = (float)(v & 255u) - 128.f;
    float hv1 = (float)((v >> 8) & 255u) - 128.f;
    int ch = lane * 2;
    ss = hv0 * att_s[ch] + hv1 * att_s[ch + 1];
    sd = hv0 * att_d[ch] + hv1 * att_d[ch + 1];
  } else {
    float hv = (float)((const unsigned char*)hq)[(size_t)node * 64 + lane] - 128.f;
    ss = hv * att_s[lane];
    sd = hv * att_d[lane];
  }
  #pragma unroll
  for (int d = (H == 1 ? 32 : 16); d >= 1; d >>= 1) {
    ss += __shfl_xor(ss, d);
    sd += __shfl_xor(sd, d);
  }
  int gl = (H == 2) ? (lane & 31) : lane;
  int hd = (H == 2) ? (lane >> 5) : 0;
  if (gl == 0) {
    asrc[(size_t)node * H + hd] = ss * sv;
    adst[(size_t)node * H + hd] = sd * sv;
  }
}

// ====== softmax-aggregate: flash-style, biased-u8 rows, LDS p-broadcast, 8-deep MLP ====
template <int H, bool ELU_OUT, bool F32OUT>
__global__ __launch_bounds__(256) void agg_gather(const void* __restrict__ hq,
                                                  const float* __restrict__ scl,
                                                  const float* __restrict__ asrc,
                                                  const float* __restrict__ adst,
                                                  const int* __restrict__ offs,
                                                  const int* __restrict__ ssrc,
                                                  const float* __restrict__ bias,
                                                  void* __restrict__ outv, int n) {
  __shared__ float pshare[4][64];
  __shared__ int vshare[4][64];  // H==1 only: row byte offsets
  const int tid = threadIdx.x;
  const int wid = tid >> 6;
  int node = (int)((blockIdx.x * (unsigned)blockDim.x + tid) >> 6);
  int lane = tid & 63;
  if (node >= n) return;  // node uniform per wave -> whole wave exits
  const int hd = lane >> 5;
  const int beg = offs[node], end = offs[node + 1];
  const unsigned short* hq16 = (const unsigned short*)hq;
  const unsigned char* hqb = (const unsigned char*)hq;

  float adh, m, acc0, acc1, d;
  float SPF = 0.f;  // running sum of folded p (for the -128 bias correction)
  const float s_self = scl[node];
  if constexpr (H == 2) {
    float2 adv = ((const float2*)adst)[node];
    float2 asv = ((const float2*)asrc)[node];
    adh = hd ? adv.y : adv.x;
    m = lrelu02((hd ? asv.y : asv.x) + adh);  // e_self per head
    unsigned int v = hq16[((size_t)node << 6) + lane];  // ch 2l,2l+1
    acc0 = s_self * ((float)(v & 255u) - 128.f);  // p_self = 1, exact decode
    acc1 = s_self * ((float)((v >> 8) & 255u) - 128.f);
  } else {
    adh = adst[node];
    m = lrelu02(asrc[node] + adh);
    if (hd == 0) {
      unsigned int v = hq16[((size_t)node << 5) + lane];
      acc0 = s_self * ((float)(v & 255u) - 128.f);
      acc1 = s_self * ((float)((v >> 8) & 255u) - 128.f);
    } else {
      acc0 = 0.f; acc1 = 0.f;
    }
  }
  d = 1.f;  // p_self

  constexpr int CH = (H == 2) ? 32 : 64;
  const int lvoff = (lane & 31) * 2;  // H==1 byte offset within row
  for (int pos = beg; pos < end; pos += CH) {
    const int len = min(CH, end - pos);
    int li = (H == 2) ? (lane & 31) : lane;
    bool valid = li < len;
    int s_l = valid ? ssrc[pos + li] : 0;      // pad: node 0 (safe), p will be 0
    float scl_l = valid ? scl[s_l] : 0.f;
    float e_l;
    if constexpr (H == 2) {
      float a = asrc[(s_l << 1) + hd];
      e_l = valid ? lrelu02(a + adh) : NEG_INF;
    } else {
      float a = asrc[s_l];
      e_l = valid ? lrelu02(a + adh) : NEG_INF;
    }
    float mc = e_l;
    #pragma unroll
    for (int dlt = CH >> 1; dlt >= 1; dlt >>= 1) mc = fmaxf(mc, __shfl_xor(mc, dlt));
    float m_new = fmaxf(m, mc);
    float f = __expf(m - m_new);
    float p_l = __expf(e_l - m_new);  // 0 for invalid lanes
    float sc = p_l;
    #pragma unroll
    for (int dlt = CH >> 1; dlt >= 1; dlt >>= 1) sc += __shfl_xor(sc, dlt);
    d = d * f + sc;
    acc0 *= f; acc1 *= f;
    m = m_new;
    p_l *= scl_l;  // fold per-row dequant scale (post-denominator)

    pshare[wid][lane] = p_l;
    float spf = p_l;
    if constexpr (H == 2) {
      #pragma unroll
      for (int dlt = 16; dlt >= 1; dlt >>= 1) spf += __shfl_xor(spf, dlt);  // per head
    } else {
      vshare[wid][lane] = s_l << 6;  // row byte offset (64 B rows)
      #pragma unroll
      for (int dlt = 32; dlt >= 1; dlt >>= 1) spf += __shfl_xor(spf, dlt);  // all edges
    }
    SPF = SPF * f + spf;

    if constexpr (H == 2) {
      const int ng = (len + 7) >> 3;
      for (int g = 0; g < ng; g++) {
        const int jb = g * 8;  // wave-uniform
        unsigned short v[8];
        #pragma unroll
        for (int k = 0; k < 8; k++) {
          int s = rl_i(s_l, jb + k);  // SGPR row id -> SALU addressing
          v[k] = hq16[((size_t)(unsigned)s << 6) + lane];
        }
        float pv[8];
        #pragma unroll
        for (int k = 0; k < 8; k++) pv[k] = pshare[wid][hd * 32 + jb + k];
        #pragma unroll
        for (int k = 0; k < 8; k++) {
          unsigned int w = v[k];
          acc0 = fmaf(pv[k], (float)(w & 255u), acc0);
          acc1 = fmaf(pv[k], (float)((w >> 8) & 255u), acc1);
        }
      }
    } else {
      const int npair = (len + 1) >> 1;
      const int ng = (npair + 7) >> 3;
      for (int g = 0; g < ng; g++) {
        const int jb = g * 16;  // edge base, wave-uniform
        unsigned short v[8];
        #pragma unroll
        for (int k = 0; k < 8; k++) {
          int voff = vshare[wid][jb + 2 * k + hd];   // ds_read, imm offset + hd base
          v[k] = *(const unsigned short*)(hqb + (unsigned)voff + lvoff);
        }
        float pv[8];
        #pragma unroll
        for (int k = 0; k < 8; k++) pv[k] = pshare[wid][jb + 2 * k + hd];
        #pragma unroll
        for (int k = 0; k < 8; k++) {
          unsigned int w = v[k];
          acc0 = fmaf(pv[k], (float)(w & 255u), acc0);
          acc1 = fmaf(pv[k], (float)((w >> 8) & 255u), acc1);
        }
      }
    }
  }

  if constexpr (H == 1) {  // halves accumulated different edges
    acc0 += __shfl_xor(acc0, 32);
    acc1 += __shfl_xor(acc1, 32);
  }
  // remove the +128 bias: edge contributions become p*(u-128)
  acc0 = fmaf(-128.f, SPF, acc0);
  acc1 = fmaf(-128.f, SPF, acc1);

  const float inv = 1.f / d;
  if constexpr (H == 2) {
    float2 bv = ((const float2*)bias)[lane];
    float v0 = acc0 * inv + bv.x;
    float v1 = acc1 * inv + bv.y;
    if (ELU_OUT) {
      v0 = v0 > 0.f ? v0 : (__expf(v0) - 1.f);
      v1 = v1 > 0.f ? v1 : (__expf(v1) - 1.f);
    }
    if constexpr (F32OUT) {
      ((float2*)outv)[(size_t)node * 64 + lane] = make_float2(v0, v1);
    } else {
      unsigned int pk = (unsigned int)f2bf(v0) | ((unsigned int)f2bf(v1) << 16);
      ((unsigned int*)outv)[(size_t)node * 64 + lane] = pk;
    }
  } else {
    if (hd == 0) {
      float2 bv = ((const float2*)bias)[lane];
      float v0 = acc0 * inv + bv.x;
      float v1 = acc1 * inv + bv.y;
      if (ELU_OUT) {
        v0 = v0 > 0.f ? v0 : (__expf(v0) - 1.f);
        v1 = v1 > 0.f ? v1 : (__expf(v1) - 1.f);
      }
      if constexpr (F32OUT) {
        ((float2*)outv)[(size_t)node * 32 + lane] = make_float2(v0, v1);
      } else {
        unsigned int pk = (unsigned int)f2bf(v0) | ((unsigned int)f2bf(v1) << 16);
        ((unsigned int*)outv)[(size_t)node * 32 + lane] = pk;
      }
    }
  }
}

// ============================ launch ============================
extern "C" void kernel_launch(void* const* d_in, const int* in_sizes, int n_in,
                              void* d_out, int out_size, void* d_ws, size_t ws_size,
                              hipStream_t stream) {
  const int N = in_sizes[0] / FIN;      // 100000
  const int E = in_sizes[1] / 2;        // 1600000

  const void*  x   = d_in[0];
  const int*   ei  = (const int*)d_in[1];
  const float* W1  = (const float*)d_in[2];
  const float* as1 = (const float*)d_in[3];
  const float* ad1 = (const float*)d_in[4];
  const float* b1  = (const float*)d_in[5];
  const float* W2  = (const float*)d_in[6];
  const float* as2 = (const float*)d_in[7];
  const float* ad2 = (const float*)d_in[8];
  const float* b2  = (const float*)d_in[9];

  const int* e_src = ei;
  const int* e_dst = ei + E;

  char* p = (char*)d_ws;
  auto carve = [&](size_t bytes) {
    char* q = p;
    p += (bytes + 255) & ~(size_t)255;
    return (void*)q;
  };
  unsigned char* h1q = (unsigned char*)carve((size_t)N * 128);     // u8 rows, layer1
  float* scl1        = (float*)carve((size_t)N * 4);
  unsigned char* h2q = (unsigned char*)carve((size_t)N * 64);      // u8 rows, layer2
  float* scl2        = (float*)carve((size_t)N * 4);
  unsigned short* buf2 = (unsigned short*)carve((size_t)N * HC1 * 2);  // bf16 layer1 out
  float* asrc1 = (float*)carve((size_t)N * 2 * 4);
  float* adst1 = (float*)carve((size_t)N * 2 * 4);
  float* asrc2 = (float*)carve((size_t)N * 4);
  float* adst2 = (float*)carve((size_t)N * 4);
  int* counts  = (int*)carve((size_t)N * 4);
  int* offs    = (int*)carve((size_t)(N + 1) * 4);
  int* bsum    = (int*)carve(512 * 4);
  int* bhist   = (int*)carve((size_t)2 * 512 * 4);  // bhist + gcur, one memset
  int* gcur    = bhist + 512;
  int* boffs   = (int*)carve(513 * 4);
  unsigned int* sorted = (unsigned int*)carve((size_t)E * 4);
  int* ssrc    = (int*)carve((size_t)E * 4);

  const int NB = (N + 255) >> 8;
  const int nb = (N + 255) / 256;
  const int sgrid = (E + EPB - 1) / EPB;
  const int wgrid = (int)(((size_t)N * 64 + 255) / 256);
  const int ggrid = (N + 127) / 128;

  // ---- CSR build (bucket-sorted, shared by both layers) ----
  hipMemsetAsync(bhist, 0, (size_t)2 * 512 * 4, stream);
  bucket_hist<<<sgrid, 256, 0, stream>>>(e_dst, bhist, E, NB);
  scan_buckets<<<1, 512, 0, stream>>>(bhist, boffs, NB);
  bucket_scatter<<<sgrid, 256, 0, stream>>>(e_src, e_dst, boffs, gcur, sorted, E, NB);
  bucket_count<<<NB, 256, 0, stream>>>(sorted, boffs, counts, N);
  scan_block<<<nb, 256, 0, stream>>>(counts, offs, bsum, N);
  scan_top<<<1, 512, 0, stream>>>(bsum, nb);
  scan_add<<<(N + 256) / 256, 256, 0, stream>>>(offs, bsum, N, E);
  bucket_place<<<NB, 256, 0, stream>>>(sorted, boffs, offs, ssrc, N);

  // ---- layer 1 ----
  gemm_mfma<128, true><<<ggrid, 256, 0, stream>>>(x, W1, h1q, scl1, N);
  attn_logits<2><<<wgrid, 256, 0, stream>>>(h1q, scl1, as1, ad1, asrc1, adst1, N);
  agg_gather<2, true, false><<<wgrid, 256, 0, stream>>>(h1q, scl1, asrc1, adst1, offs, ssrc,
                                                        b1, buf2, N);

  // ---- layer 2 ----
  gemm_mfma<64, false><<<ggrid, 256, 0, stream>>>(buf2, W2, h2q, scl2, N);
  attn_logits<1><<<wgrid, 256, 0, stream>>>(h2q, scl2, as2, ad2, asrc2, adst2, N);
  agg_gather<1, false, true><<<wgrid, 256, 0, stream>>>(h2q, scl2, asrc2, adst2, offs, ssrc,
                                                        b2, d_out, N);
}

// Round 10
// 310.275 us; speedup vs baseline: 1.5395x; 1.1152x over previous
//
#include <hip/hip_runtime.h>
#include <hip/hip_bf16.h>
#include <cstdint>
#include <cstddef>

// Inputs/outputs fp32. Node features stored as BIASED uint8 (q+128) + per-row
// scale. Round-10: dispatch-count fusion — CSR tail fused into one kernel
// (offs[d] = boffs[d>>8] + in-bucket prefix), attention logits fused into the
// MFMA GEMM epilogue (logits now computed from fp32 accumulators).
static constexpr int FIN = 128;
static constexpr int HC1 = 128;  // layer1: H=2, C=64, concat
static constexpr int EPB = 4096; // edges per block in bucket_scatter

typedef __attribute__((ext_vector_type(8))) short short8;   // 8 bf16 = 4 VGPRs
typedef __attribute__((ext_vector_type(4))) float f32x4;    // MFMA acc

__device__ __forceinline__ float bf2f(unsigned int u) { return __uint_as_float(u << 16); }
__device__ __forceinline__ unsigned short f2bf(float f) {  // round-to-nearest-even
  unsigned int u = __float_as_uint(f);
  return (unsigned short)((u + 0x7fff + ((u >> 16) & 1)) >> 16);
}
__device__ __forceinline__ float lrelu02(float x) { return x > 0.f ? x : 0.2f * x; }
__device__ __forceinline__ int rl_i(int v, int l) { return __builtin_amdgcn_readlane(v, l); }
__device__ __forceinline__ unsigned int q8b(float x, float inv) {  // biased uint8
  float q = fminf(fmaxf(x * inv, -127.f), 127.f);
  return (unsigned int)((int)rintf(q) + 128) & 255u;
}
#define NEG_INF __int_as_float(0xff800000)

// ============================ bucket-sorted CSR build ============================
__global__ __launch_bounds__(256) void bucket_hist(const int* __restrict__ dst,
                                                   int* __restrict__ bhist, int E, int NB) {
  __shared__ int lh[512];
  int t = threadIdx.x;
  lh[t] = 0; lh[t + 256] = 0;
  __syncthreads();
  int e0 = blockIdx.x * EPB;
  #pragma unroll
  for (int i = 0; i < EPB / 256; i++) {
    int e = e0 + i * 256 + t;
    if (e < E) atomicAdd(&lh[dst[e] >> 8], 1);
  }
  __syncthreads();
  for (int x = t; x < NB; x += 256) {
    int c = lh[x];
    if (c > 0) atomicAdd(&bhist[x], c);
  }
}

__global__ __launch_bounds__(512) void scan_buckets(const int* __restrict__ bhist,
                                                    int* __restrict__ boffs, int n) {
  __shared__ int sh[512];
  int t = threadIdx.x;
  int v = (t < n) ? bhist[t] : 0;
  sh[t] = v; __syncthreads();
  for (int d = 1; d < 512; d <<= 1) {
    int w = (t >= d) ? sh[t - d] : 0;
    __syncthreads();
    sh[t] += w;
    __syncthreads();
  }
  if (t <= n) boffs[t] = sh[t] - v;  // boffs[n] = E (total)
}

__global__ __launch_bounds__(256) void bucket_scatter(const int* __restrict__ src,
                                                      const int* __restrict__ dst,
                                                      const int* __restrict__ boffs,
                                                      int* __restrict__ gcur,
                                                      unsigned int* __restrict__ sorted,
                                                      int E, int NB) {
  __shared__ int lh[512];
  int t = threadIdx.x;
  lh[t] = 0; lh[t + 256] = 0;
  __syncthreads();
  int e0 = blockIdx.x * EPB;
  #pragma unroll
  for (int i = 0; i < EPB / 256; i++) {
    int e = e0 + i * 256 + t;
    if (e < E) atomicAdd(&lh[dst[e] >> 8], 1);
  }
  __syncthreads();
  for (int x = t; x < NB; x += 256) {
    int c = lh[x];
    lh[x] = (c > 0) ? (boffs[x] + atomicAdd(&gcur[x], c)) : 0;
  }
  __syncthreads();
  #pragma unroll
  for (int i = 0; i < EPB / 256; i++) {
    int e = e0 + i * 256 + t;
    if (e < E) {
      int d = dst[e];
      int pos = atomicAdd(&lh[d >> 8], 1);
      sorted[pos] = ((unsigned int)src[e] << 8) | (unsigned int)(d & 255);
    }
  }
}

// Fused: per-bucket count -> LDS scan -> offs write -> place.
// offs[d] = boffs[d>>8] + exclusive-prefix of per-dst counts within the bucket.
__global__ __launch_bounds__(256) void bucket_place_fused(const unsigned int* __restrict__ sorted,
                                                          const int* __restrict__ boffs,
                                                          int* __restrict__ offs,
                                                          int* __restrict__ ssrc,
                                                          int N, int E) {
  __shared__ int cnt[256];
  __shared__ int pref[256];
  int b = blockIdx.x, t = threadIdx.x;
  cnt[t] = 0;
  __syncthreads();
  int beg = boffs[b], end = boffs[b + 1];
  for (int p = beg + t; p < end; p += 256)
    atomicAdd(&cnt[sorted[p] & 255u], 1);
  __syncthreads();
  int v = cnt[t];
  pref[t] = v; __syncthreads();
  for (int d = 1; d < 256; d <<= 1) {
    int w = (t >= d) ? pref[t - d] : 0;
    __syncthreads();
    pref[t] += w;
    __syncthreads();
  }
  int excl = pref[t] - v;          // exclusive within bucket
  int node = b * 256 + t;
  if (node < N) offs[node] = beg + excl;
  if (b == 0 && t == 0) offs[N] = E;
  cnt[t] = beg + excl;             // cursor starts at CSR slot
  __syncthreads();
  for (int p = beg + t; p < end; p += 256) {
    unsigned int pk = sorted[p];
    int dl = pk & 255u;
    int r = atomicAdd(&cnt[dl], 1);
    ssrc[r] = (int)(pk >> 8);
  }
}

// ===== MFMA GEMM (K=128) -> biased uint8 rows + per-row scale + fused attn logits ====
// Block = 4 waves x 128 rows; W^T staged bf16 in LDS. Wave w: rows [blk*128+w*32,+32).
// mfma_f32_16x16x32_bf16 C layout: col=lane&15, row=quad*4+reg.
// Logits asrc/adst computed from fp32 acc (pre-quantization) in the epilogue.
template <int COLS, bool AF32>
__global__ __launch_bounds__(256) void gemm_mfma(const void* __restrict__ Av,
                                                 const float* __restrict__ Wv,
                                                 const float* __restrict__ att_s,
                                                 const float* __restrict__ att_d,
                                                 unsigned char* __restrict__ Cq,
                                                 float* __restrict__ scl,
                                                 float* __restrict__ asrc,
                                                 float* __restrict__ adst,
                                                 int nrows) {
  constexpr int NT = COLS / 16;       // col-tiles: 8 or 4
  constexpr int H = COLS / 64;        // 2 or 1
  __shared__ unsigned short WT[COLS][136];            // [col][k], +8 bf16 pad
  __shared__ __align__(16) unsigned char pack[4][16 * COLS];

  const int tid = threadIdx.x;
  // ---- stage W^T (fp32 -> bf16), coalesced reads, one-time ----
  constexpr int NPC = COLS / 4;
  for (int idx = tid; idx < 128 * NPC; idx += 256) {
    int k = idx / NPC;
    int n0 = (idx - k * NPC) * 4;
    float4 wv = *(const float4*)(Wv + (size_t)k * COLS + n0);
    WT[n0 + 0][k] = f2bf(wv.x);
    WT[n0 + 1][k] = f2bf(wv.y);
    WT[n0 + 2][k] = f2bf(wv.z);
    WT[n0 + 3][k] = f2bf(wv.w);
  }

  const int w = tid >> 6, lane = tid & 63;
  const int quad = lane >> 4, cl = lane & 15;
  const int rbase = blockIdx.x * 128 + w * 32;

  // attention vectors for this lane's columns (ch = ct*16+cl)
  float asv[NT], adv[NT];
  #pragma unroll
  for (int ct = 0; ct < NT; ct++) {
    asv[ct] = att_s[ct * 16 + cl];
    adv[ct] = att_d[ct * 16 + cl];
  }
  __syncthreads();

  f32x4 acc[2][NT];
  #pragma unroll
  for (int rt = 0; rt < 2; rt++)
    #pragma unroll
    for (int ct = 0; ct < NT; ct++) acc[rt][ct] = (f32x4){0.f, 0.f, 0.f, 0.f};

  #pragma unroll
  for (int kc = 0; kc < 4; kc++) {
    const int k0 = kc * 32 + quad * 8;
    short8 a[2];
    #pragma unroll
    for (int rt = 0; rt < 2; rt++) {
      int row = rbase + rt * 16 + cl;
      row = min(row, nrows - 1);  // clamp; out-of-range rows discarded at store
      if constexpr (AF32) {
        const float* ap = (const float*)Av + (size_t)row * 128 + k0;
        float4 f0 = *(const float4*)ap;
        float4 f1 = *(const float4*)(ap + 4);
        short8 t;
        t[0] = (short)f2bf(f0.x); t[1] = (short)f2bf(f0.y);
        t[2] = (short)f2bf(f0.z); t[3] = (short)f2bf(f0.w);
        t[4] = (short)f2bf(f1.x); t[5] = (short)f2bf(f1.y);
        t[6] = (short)f2bf(f1.z); t[7] = (short)f2bf(f1.w);
        a[rt] = t;
      } else {
        a[rt] = *(const short8*)((const unsigned short*)Av + (size_t)row * 128 + k0);
      }
    }
    #pragma unroll
    for (int ct = 0; ct < NT; ct++) {
      short8 b = *(const short8*)&WT[ct * 16 + cl][k0];
      #pragma unroll
      for (int rt = 0; rt < 2; rt++)
        acc[rt][ct] = __builtin_amdgcn_mfma_f32_16x16x32_bf16(a[rt], b, acc[rt][ct], 0, 0, 0);
    }
  }

  // ---- epilogue: fused logits + per-row absmax -> biased u8 -> coalesced store ----
  #pragma unroll
  for (int rt = 0; rt < 2; rt++) {
    #pragma unroll
    for (int r = 0; r < 4; r++) {
      int grow = rbase + rt * 16 + quad * 4 + r;
      // attention logit partials (head h = ct>=NT/2 for H==2)
      float s0 = 0.f, s1 = 0.f, d0 = 0.f, d1 = 0.f;
      float mx = 0.f;
      #pragma unroll
      for (int ct = 0; ct < NT; ct++) {
        float av = acc[rt][ct][r];
        mx = fmaxf(mx, fabsf(av));
        if (H == 2 && ct >= NT / 2) {
          s1 = fmaf(av, asv[ct], s1);
          d1 = fmaf(av, adv[ct], d1);
        } else {
          s0 = fmaf(av, asv[ct], s0);
          d0 = fmaf(av, adv[ct], d0);
        }
      }
      #pragma unroll
      for (int dd = 8; dd >= 1; dd >>= 1) {
        mx = fmaxf(mx, __shfl_xor(mx, dd));
        s0 += __shfl_xor(s0, dd);
        d0 += __shfl_xor(d0, dd);
        if (H == 2) {
          s1 += __shfl_xor(s1, dd);
          d1 += __shfl_xor(d1, dd);
        }
      }
      float inv = mx > 0.f ? 127.f / mx : 0.f;
      if (cl == 0 && grow < nrows) {
        scl[grow] = mx * (1.f / 127.f);
        if (H == 2) {
          ((float2*)asrc)[grow] = make_float2(s0, s1);
          ((float2*)adst)[grow] = make_float2(d0, d1);
        } else {
          asrc[grow] = s0;
          adst[grow] = d0;
        }
      }
      #pragma unroll
      for (int ct = 0; ct < NT; ct++)
        pack[w][(quad * 4 + r) * COLS + ct * 16 + cl] =
            (unsigned char)q8b(acc[rt][ct][r], inv);
    }
    __syncthreads();  // order LDS writes before reads (uniform barrier)
    if constexpr (COLS == 128) {
      #pragma unroll
      for (int i = 0; i < 2; i++) {
        int off = i * 1024 + lane * 16;
        uint4 v = *(const uint4*)&pack[w][off];
        int grow = rbase + rt * 16 + (off >> 7);
        if (grow < nrows)
          *(uint4*)(Cq + (size_t)grow * 128 + (off & 127)) = v;
      }
    } else {
      int off = lane * 16;
      uint4 v = *(const uint4*)&pack[w][off];
      int grow = rbase + rt * 16 + (off >> 6);
      if (grow < nrows)
        *(uint4*)(Cq + (size_t)grow * 64 + (off & 63)) = v;
    }
    __syncthreads();  // protect pack slab before rt=1 overwrites
  }
}

// ====== softmax-aggregate: flash-style, biased-u8 rows, LDS p-broadcast, 8-deep MLP ====
template <int H, bool ELU_OUT, bool F32OUT>
__global__ __launch_bounds__(256) void agg_gather(const void* __restrict__ hq,
                                                  const float* __restrict__ scl,
                                                  const float* __restrict__ asrc,
                                                  const float* __restrict__ adst,
                                                  const int* __restrict__ offs,
                                                  const int* __restrict__ ssrc,
                                                  const float* __restrict__ bias,
                                                  void* __restrict__ outv, int n) {
  __shared__ float pshare[4][64];
  __shared__ int vshare[4][64];  // H==1 only: row byte offsets
  const int tid = threadIdx.x;
  const int wid = tid >> 6;
  int node = (int)((blockIdx.x * (unsigned)blockDim.x + tid) >> 6);
  int lane = tid & 63;
  if (node >= n) return;  // node uniform per wave -> whole wave exits
  const int hd = lane >> 5;
  const int beg = offs[node], end = offs[node + 1];
  const unsigned short* hq16 = (const unsigned short*)hq;
  const unsigned char* hqb = (const unsigned char*)hq;

  float adh, m, acc0, acc1, d;
  float SPF = 0.f;  // running sum of folded p (for the -128 bias correction)
  const float s_self = scl[node];
  if constexpr (H == 2) {
    float2 adv = ((const float2*)adst)[node];
    float2 asv = ((const float2*)asrc)[node];
    adh = hd ? adv.y : adv.x;
    m = lrelu02((hd ? asv.y : asv.x) + adh);  // e_self per head
    unsigned int v = hq16[((size_t)node << 6) + lane];  // ch 2l,2l+1
    acc0 = s_self * ((float)(v & 255u) - 128.f);  // p_self = 1, exact decode
    acc1 = s_self * ((float)((v >> 8) & 255u) - 128.f);
  } else {
    adh = adst[node];
    m = lrelu02(asrc[node] + adh);
    if (hd == 0) {
      unsigned int v = hq16[((size_t)node << 5) + lane];
      acc0 = s_self * ((float)(v & 255u) - 128.f);
      acc1 = s_self * ((float)((v >> 8) & 255u) - 128.f);
    } else {
      acc0 = 0.f; acc1 = 0.f;
    }
  }
  d = 1.f;  // p_self

  constexpr int CH = (H == 2) ? 32 : 64;
  const int lvoff = (lane & 31) * 2;  // H==1 byte offset within row
  for (int pos = beg; pos < end; pos += CH) {
    const int len = min(CH, end - pos);
    int li = (H == 2) ? (lane & 31) : lane;
    bool valid = li < len;
    int s_l = valid ? ssrc[pos + li] : 0;      // pad: node 0 (safe), p will be 0
    float scl_l = valid ? scl[s_l] : 0.f;
    float e_l;
    if constexpr (H == 2) {
      float a = asrc[(s_l << 1) + hd];
      e_l = valid ? lrelu02(a + adh) : NEG_INF;
    } else {
      float a = asrc[s_l];
      e_l = valid ? lrelu02(a + adh) : NEG_INF;
    }
    float mc = e_l;
    #pragma unroll
    for (int dlt = CH >> 1; dlt >= 1; dlt >>= 1) mc = fmaxf(mc, __shfl_xor(mc, dlt));
    float m_new = fmaxf(m, mc);
    float f = __expf(m - m_new);
    float p_l = __expf(e_l - m_new);  // 0 for invalid lanes
    float sc = p_l;
    #pragma unroll
    for (int dlt = CH >> 1; dlt >= 1; dlt >>= 1) sc += __shfl_xor(sc, dlt);
    d = d * f + sc;
    acc0 *= f; acc1 *= f;
    m = m_new;
    p_l *= scl_l;  // fold per-row dequant scale (post-denominator)

    pshare[wid][lane] = p_l;
    float spf = p_l;
    if constexpr (H == 2) {
      #pragma unroll
      for (int dlt = 16; dlt >= 1; dlt >>= 1) spf += __shfl_xor(spf, dlt);  // per head
    } else {
      vshare[wid][lane] = s_l << 6;  // row byte offset (64 B rows)
      #pragma unroll
      for (int dlt = 32; dlt >= 1; dlt >>= 1) spf += __shfl_xor(spf, dlt);  // all edges
    }
    SPF = SPF * f + spf;

    if constexpr (H == 2) {
      const int ng = (len + 7) >> 3;
      for (int g = 0; g < ng; g++) {
        const int jb = g * 8;  // wave-uniform
        unsigned short v[8];
        #pragma unroll
        for (int k = 0; k < 8; k++) {
          int s = rl_i(s_l, jb + k);  // SGPR row id -> SALU addressing
          v[k] = hq16[((size_t)(unsigned)s << 6) + lane];
        }
        float pv[8];
        #pragma unroll
        for (int k = 0; k < 8; k++) pv[k] = pshare[wid][hd * 32 + jb + k];
        #pragma unroll
        for (int k = 0; k < 8; k++) {
          unsigned int w = v[k];
          acc0 = fmaf(pv[k], (float)(w & 255u), acc0);
          acc1 = fmaf(pv[k], (float)((w >> 8) & 255u), acc1);
        }
      }
    } else {
      const int npair = (len + 1) >> 1;
      const int ng = (npair + 7) >> 3;
      for (int g = 0; g < ng; g++) {
        const int jb = g * 16;  // edge base, wave-uniform
        unsigned short v[8];
        #pragma unroll
        for (int k = 0; k < 8; k++) {
          int voff = vshare[wid][jb + 2 * k + hd];   // ds_read, imm offset + hd base
          v[k] = *(const unsigned short*)(hqb + (unsigned)voff + lvoff);
        }
        float pv[8];
        #pragma unroll
        for (int k = 0; k < 8; k++) pv[k] = pshare[wid][jb + 2 * k + hd];
        #pragma unroll
        for (int k = 0; k < 8; k++) {
          unsigned int w = v[k];
          acc0 = fmaf(pv[k], (float)(w & 255u), acc0);
          acc1 = fmaf(pv[k], (float)((w >> 8) & 255u), acc1);
        }
      }
    }
  }

  if constexpr (H == 1) {  // halves accumulated different edges
    acc0 += __shfl_xor(acc0, 32);
    acc1 += __shfl_xor(acc1, 32);
  }
  // remove the +128 bias: edge contributions become p*(u-128)
  acc0 = fmaf(-128.f, SPF, acc0);
  acc1 = fmaf(-128.f, SPF, acc1);

  const float inv = 1.f / d;
  if constexpr (H == 2) {
    float2 bv = ((const float2*)bias)[lane];
    float v0 = acc0 * inv + bv.x;
    float v1 = acc1 * inv + bv.y;
    if (ELU_OUT) {
      v0 = v0 > 0.f ? v0 : (__expf(v0) - 1.f);
      v1 = v1 > 0.f ? v1 : (__expf(v1) - 1.f);
    }
    if constexpr (F32OUT) {
      ((float2*)outv)[(size_t)node * 64 + lane] = make_float2(v0, v1);
    } else {
      unsigned int pk = (unsigned int)f2bf(v0) | ((unsigned int)f2bf(v1) << 16);
      ((unsigned int*)outv)[(size_t)node * 64 + lane] = pk;
    }
  } else {
    if (hd == 0) {
      float2 bv = ((const float2*)bias)[lane];
      float v0 = acc0 * inv + bv.x;
      float v1 = acc1 * inv + bv.y;
      if (ELU_OUT) {
        v0 = v0 > 0.f ? v0 : (__expf(v0) - 1.f);
        v1 = v1 > 0.f ? v1 : (__expf(v1) - 1.f);
      }
      if constexpr (F32OUT) {
        ((float2*)outv)[(size_t)node * 32 + lane] = make_float2(v0, v1);
      } else {
        unsigned int pk = (unsigned int)f2bf(v0) | ((unsigned int)f2bf(v1) << 16);
        ((unsigned int*)outv)[(size_t)node * 32 + lane] = pk;
      }
    }
  }
}

// ============================ launch ============================
extern "C" void kernel_launch(void* const* d_in, const int* in_sizes, int n_in,
                              void* d_out, int out_size, void* d_ws, size_t ws_size,
                              hipStream_t stream) {
  const int N = in_sizes[0] / FIN;      // 100000
  const int E = in_sizes[1] / 2;        // 1600000

  const void*  x   = d_in[0];
  const int*   ei  = (const int*)d_in[1];
  const float* W1  = (const float*)d_in[2];
  const float* as1 = (const float*)d_in[3];
  const float* ad1 = (const float*)d_in[4];
  const float* b1  = (const float*)d_in[5];
  const float* W2  = (const float*)d_in[6];
  const float* as2 = (const float*)d_in[7];
  const float* ad2 = (const float*)d_in[8];
  const float* b2  = (const float*)d_in[9];

  const int* e_src = ei;
  const int* e_dst = ei + E;

  char* p = (char*)d_ws;
  auto carve = [&](size_t bytes) {
    char* q = p;
    p += (bytes + 255) & ~(size_t)255;
    return (void*)q;
  };
  unsigned char* h1q = (unsigned char*)carve((size_t)N * 128);     // u8 rows, layer1
  float* scl1        = (float*)carve((size_t)N * 4);
  unsigned char* h2q = (unsigned char*)carve((size_t)N * 64);      // u8 rows, layer2
  float* scl2        = (float*)carve((size_t)N * 4);
  unsigned short* buf2 = (unsigned short*)carve((size_t)N * HC1 * 2);  // bf16 layer1 out
  float* asrc1 = (float*)carve((size_t)N * 2 * 4);
  float* adst1 = (float*)carve((size_t)N * 2 * 4);
  float* asrc2 = (float*)carve((size_t)N * 4);
  float* adst2 = (float*)carve((size_t)N * 4);
  int* offs    = (int*)carve((size_t)(N + 1) * 4);
  int* bhist   = (int*)carve((size_t)2 * 512 * 4);  // bhist + gcur, one memset
  int* gcur    = bhist + 512;
  int* boffs   = (int*)carve(513 * 4);
  unsigned int* sorted = (unsigned int*)carve((size_t)E * 4);
  int* ssrc    = (int*)carve((size_t)E * 4);

  const int NB = (N + 255) >> 8;               // 391 buckets
  const int sgrid = (E + EPB - 1) / EPB;       // 391
  const int wgrid = (int)(((size_t)N * 64 + 255) / 256);
  const int ggrid = (N + 127) / 128;

  // ---- CSR build (bucket-sorted, shared by both layers): 5 dispatches ----
  hipMemsetAsync(bhist, 0, (size_t)2 * 512 * 4, stream);
  bucket_hist<<<sgrid, 256, 0, stream>>>(e_dst, bhist, E, NB);
  scan_buckets<<<1, 512, 0, stream>>>(bhist, boffs, NB);
  bucket_scatter<<<sgrid, 256, 0, stream>>>(e_src, e_dst, boffs, gcur, sorted, E, NB);
  bucket_place_fused<<<NB, 256, 0, stream>>>(sorted, boffs, offs, ssrc, N, E);

  // ---- layer 1 (GEMM + fused logits, then gather) ----
  gemm_mfma<128, true><<<ggrid, 256, 0, stream>>>(x, W1, as1, ad1, h1q, scl1,
                                                  asrc1, adst1, N);
  agg_gather<2, true, false><<<wgrid, 256, 0, stream>>>(h1q, scl1, asrc1, adst1, offs, ssrc,
                                                        b1, buf2, N);

  // ---- layer 2 ----
  gemm_mfma<64, false><<<ggrid, 256, 0, stream>>>(buf2, W2, as2, ad2, h2q, scl2,
                                                  asrc2, adst2, N);
  agg_gather<1, false, true><<<wgrid, 256, 0, stream>>>(h2q, scl2, asrc2, adst2, offs, ssrc,
                                                        b2, d_out, N);
}